// Round 5
// baseline (3936.166 us; speedup 1.0000x reference)
//
#include <hip/hip_runtime.h>
#include <hip/hip_bf16.h>

#define T_    16
#define C_    64
#define H_    48
#define W_    48
#define HW_   2304
#define THW_  36864
#define CTHW_ 2359296
#define H2_   24
#define W2_   24
#define SD_   576
#define RC_   4

__device__ __forceinline__ float sigm(float v) { return 1.f / (1.f + __expf(-v)); }

// ---------------- x2 = w_dc2 @ x  (1x1x1 conv3d) ----------------
__global__ void k_x2(const float* __restrict__ x, const float* __restrict__ w,
                     float* __restrict__ x2) {
    int idx = blockIdx.x * 256 + threadIdx.x;
    if (idx >= CTHW_) return;
    int o = idx / THW_, thw = idx % THW_;
    const float* wr = w + o * C_;
    float acc = 0.f;
    #pragma unroll 8
    for (int c = 0; c < C_; ++c) acc += wr[c] * x[c * THW_ + thw];
    x2[idx] = acc;
}

// ---------------- offset convs: 3x3 stride2 pad1 over (x + shifted x2) ----------------
// off layout: [side][t][o(2)][i(24)][j(24)]
__global__ void k_off(const float* __restrict__ x, const float* __restrict__ x2,
                      const float* __restrict__ w_l, const float* __restrict__ b_l,
                      const float* __restrict__ w_r, const float* __restrict__ b_r,
                      float* __restrict__ off) {
    int idx = blockIdx.x * 256 + threadIdx.x;
    if (idx >= 2 * T_ * 2 * H2_ * W2_) return;
    int j = idx % W2_;
    int i = (idx / W2_) % H2_;
    int o = (idx / (W2_ * H2_)) % 2;
    int t = (idx / (W2_ * H2_ * 2)) % T_;
    int side = idx / (W2_ * H2_ * 2 * T_);
    int ts = (side == 0) ? min(t + 1, T_ - 1) : max(t - 1, 0);
    const float* wgt = ((side == 0) ? w_l : w_r) + o * C_ * 9;
    float acc = ((side == 0) ? b_l : b_r)[o];
    for (int c = 0; c < C_; ++c) {
        const float* xc = x + c * THW_ + t * HW_;
        const float* x2c = x2 + c * THW_ + ts * HW_;
        for (int ki = 0; ki < 3; ++ki) {
            int hh = 2 * i - 1 + ki;
            if (hh < 0 || hh >= H_) continue;
            for (int kj = 0; kj < 3; ++kj) {
                int ww = 2 * j - 1 + kj;
                if (ww < 0 || ww >= W_) continue;
                float v = xc[hh * W_ + ww] + x2c[hh * W_ + ww];
                acc += v * wgt[c * 9 + ki * 3 + kj];
            }
        }
    }
    off[idx] = acc;
}

// ---------------- grid sample (bilinear, zeros padding) ----------
// part:  [side][t][c][sd]   partT: [side][t][sd][c]
__global__ void k_gs(const float* __restrict__ x2, const float* __restrict__ off,
                     float* __restrict__ part, float* __restrict__ partT) {
    int idx = blockIdx.x * 256 + threadIdx.x;
    if (idx >= 2 * T_ * SD_) return;
    int d = idx % W2_;
    int s = (idx / W2_) % H2_;
    int t = (idx / SD_) % T_;
    int side = idx / (SD_ * T_);
    int sd = s * W2_ + d;
    const float* offp = off + (side * T_ + t) * 2 * SD_;
    float v0 = 2.f * (float)d + offp[sd];          // channel 0 -> x coordinate
    float v1 = 2.f * (float)s + offp[SD_ + sd];    // channel 1 -> y coordinate
    float xf = 48.f * v0 / 23.f - 0.5f;
    float yf = 48.f * v1 / 23.f - 0.5f;
    float x0 = floorf(xf), y0 = floorf(yf);
    int ix0 = (int)x0, iy0 = (int)y0;
    float fx = xf - x0, fy = yf - y0;
    float w00 = (1.f - fx) * (1.f - fy), w10 = fx * (1.f - fy);
    float w01 = (1.f - fx) * fy,         w11 = fx * fy;
    bool vx0 = (ix0 >= 0 && ix0 < W_), vx1 = (ix0 + 1 >= 0 && ix0 + 1 < W_);
    bool vy0 = (iy0 >= 0 && iy0 < H_), vy1 = (iy0 + 1 >= 0 && iy0 + 1 < H_);
    int cx0 = min(max(ix0, 0), W_ - 1), cx1 = min(max(ix0 + 1, 0), W_ - 1);
    int cy0 = min(max(iy0, 0), H_ - 1), cy1 = min(max(iy0 + 1, 0), H_ - 1);
    float m00 = (vx0 && vy0) ? w00 : 0.f;
    float m10 = (vx1 && vy0) ? w10 : 0.f;
    float m01 = (vx0 && vy1) ? w01 : 0.f;
    float m11 = (vx1 && vy1) ? w11 : 0.f;
    int ts = (side == 0) ? min(t + 1, T_ - 1) : max(t - 1, 0);
    int i00 = cy0 * W_ + cx0, i10 = cy0 * W_ + cx1, i01 = cy1 * W_ + cx0, i11 = cy1 * W_ + cx1;
    for (int c = 0; c < C_; ++c) {
        const float* img = x2 + c * THW_ + ts * HW_;
        float val = m00 * img[i00] + m10 * img[i10] + m01 * img[i01] + m11 * img[i11];
        part[((size_t)(side * T_ + t) * C_ + c) * SD_ + sd] = val;
        partT[((size_t)(side * T_ + t) * SD_ + sd) * C_ + c] = val;
    }
}

// ---------------- per-(t,h,w) channel stats over sd of aff (recompute aff) -------
// block = 256 (4 waves); each wave = (side, t, group-of-4 hw)
// stats layout: [side][k(0=mean,1=max,2=var)][thw]
__global__ void k_stats(const float* __restrict__ x, const float* __restrict__ part,
                        float* __restrict__ stats) {
    int lane = threadIdx.x & 63;
    int wl = threadIdx.x >> 6;
    int wid = blockIdx.x * 4 + wl;
    int side = wid / (T_ * SD_);
    int rem = wid % (T_ * SD_);
    int t = rem / SD_;
    int grp = rem % SD_;
    int base = t * HW_ + grp * 4;
    __shared__ float xs[4][4][C_];
    #pragma unroll
    for (int g = 0; g < 4; ++g) xs[wl][g][lane] = x[lane * THW_ + base + g];
    __syncthreads();
    const float* pp = part + (size_t)(side * T_ + t) * C_ * SD_;
    float sum[4] = {0,0,0,0}, sumsq[4] = {0,0,0,0};
    float mx[4] = {-1e30f,-1e30f,-1e30f,-1e30f};
    for (int k = 0; k < 9; ++k) {
        int sd = lane + 64 * k;
        const float* p2 = pp + sd;
        float acc[4] = {0,0,0,0};
        for (int c = 0; c < C_; ++c) {
            float pv = p2[c * SD_];
            #pragma unroll
            for (int g = 0; g < 4; ++g) acc[g] += xs[wl][g][c] * pv;
        }
        #pragma unroll
        for (int g = 0; g < 4; ++g) {
            sum[g] += acc[g];
            sumsq[g] += acc[g] * acc[g];
            mx[g] = fmaxf(mx[g], acc[g]);
        }
    }
    #pragma unroll
    for (int g = 0; g < 4; ++g) {
        float s = sum[g], q = sumsq[g], m = mx[g];
        for (int o = 32; o > 0; o >>= 1) {
            s += __shfl_down(s, o);
            q += __shfl_down(q, o);
            m = fmaxf(m, __shfl_down(m, o));
        }
        if (lane == 0) {
            int thw = base + g;
            stats[(side * 3 + 0) * THW_ + thw] = s * (1.f / 576.f);
            stats[(side * 3 + 1) * THW_ + thw] = m;
            stats[(side * 3 + 2) * THW_ + thw] = (q - s * s * (1.f / 576.f)) * (1.f / 575.f);
        }
    }
}

// ---------------- y = sigmoid(conv3x3([avg,mx],w1) + conv3x3(var,w2)) --------
__global__ void k_attn(const float* __restrict__ stats, const float* __restrict__ ca_w1,
                       const float* __restrict__ ca_w2, float* __restrict__ yb) {
    int idx = blockIdx.x * 256 + threadIdx.x;
    if (idx >= 2 * THW_) return;
    int side = idx / THW_, thw = idx % THW_;
    int w = thw % W_, h = (thw / W_) % H_, t = thw / HW_;
    const float* avg = stats + (side * 3 + 0) * THW_ + t * HW_;
    const float* mxp = stats + (side * 3 + 1) * THW_ + t * HW_;
    const float* var = stats + (side * 3 + 2) * THW_ + t * HW_;
    float acc = 0.f;
    for (int ki = 0; ki < 3; ++ki) {
        int hh = h - 1 + ki;
        if (hh < 0 || hh >= H_) continue;
        for (int kj = 0; kj < 3; ++kj) {
            int ww = w - 1 + kj;
            if (ww < 0 || ww >= W_) continue;
            int p = hh * W_ + ww;
            int kk = ki * 3 + kj;
            acc += ca_w1[kk] * avg[p] + ca_w1[9 + kk] * mxp[p] + ca_w2[kk] * var[p];
        }
    }
    yb[idx] = sigm(acc);
}

// ---------------- xd = w_down @ x ----------------
__global__ void k_xd(const float* __restrict__ x, const float* __restrict__ w_down,
                     float* __restrict__ xd) {
    int idx = blockIdx.x * 256 + threadIdx.x;
    if (idx >= RC_ * THW_) return;
    int r = idx / THW_, thw = idx % THW_;
    float acc = 0.f;
    #pragma unroll 8
    for (int c = 0; c < C_; ++c) acc += w_down[r * C_ + c] * x[c * THW_ + thw];
    xd[idx] = acc;
}

// ---------------- agg0 = sum_i weights[i] * dwconv3d_i(xd) ----------------
__global__ void k_agg(const float* __restrict__ xd,
                      const float* __restrict__ w1, const float* __restrict__ b1,
                      const float* __restrict__ w2, const float* __restrict__ b2,
                      const float* __restrict__ w3, const float* __restrict__ b3,
                      const float* __restrict__ wts, float* __restrict__ agg0) {
    int idx = blockIdx.x * 256 + threadIdx.x;
    if (idx >= RC_ * THW_) return;
    int w = idx % W_;
    int h = (idx / W_) % H_;
    int t = (idx / HW_) % T_;
    int r = idx / THW_;
    const float* xr = xd + r * THW_;
    const float* wk_arr[3] = {w1, w2, w3};
    const float* bs_arr[3] = {b1, b2, b3};
    float tot = 0.f;
    for (int m = 0; m < 3; ++m) {
        int dil = m + 1;
        float acc = bs_arr[m][r];
        const float* wk = wk_arr[m] + r * 81;
        for (int kt = 0; kt < 9; ++kt) {
            int tt = t - 4 + kt;
            if (tt < 0 || tt >= T_) continue;
            for (int kh = 0; kh < 3; ++kh) {
                int hh = h + (kh - 1) * dil;
                if (hh < 0 || hh >= H_) continue;
                for (int kw = 0; kw < 3; ++kw) {
                    int wwp = w + (kw - 1) * dil;
                    if (wwp < 0 || wwp >= W_) continue;
                    acc += xr[tt * HW_ + hh * W_ + wwp] * wk[kt * 9 + kh * 3 + kw];
                }
            }
        }
        tot += acc * wts[m];
    }
    agg0[idx] = tot;
}

// ---------------- fused: both branches' reduction + gate + f32 store ----
// block = 256 per (t, group-of-4 hw)
__global__ void k_final2(const float* __restrict__ x, const float* __restrict__ part,
                         const float* __restrict__ partT, const float* __restrict__ yb,
                         const float* __restrict__ weights2, const float* __restrict__ agg0,
                         const float* __restrict__ w_back, float* __restrict__ out) {
    int t = blockIdx.x / (HW_ / 4);
    int grp = blockIdx.x % (HW_ / 4);
    int base = t * HW_ + grp * 4;
    int tid = threadIdx.x;
    __shared__ float xs[4][C_];
    __shared__ float wsd[2][4][SD_];
    __shared__ float red[256][4];
    {
        int g = tid >> 6, c = tid & 63;
        xs[g][c] = x[c * THW_ + base + g];
    }
    __syncthreads();
    for (int side = 0; side < 2; ++side) {
        float yv[4];
        #pragma unroll
        for (int g = 0; g < 4; ++g) yv[g] = yb[side * THW_ + base + g];
        const float* pp = part + (size_t)(side * T_ + t) * C_ * SD_;
        for (int sd = tid; sd < SD_; sd += 256) {
            const float* p2 = pp + sd;
            float acc[4] = {0,0,0,0};
            for (int c = 0; c < C_; ++c) {
                float pv = p2[c * SD_];
                #pragma unroll
                for (int g = 0; g < 4; ++g) acc[g] += xs[g][c] * pv;
            }
            #pragma unroll
            for (int g = 0; g < 4; ++g) wsd[side][g][sd] = sigm(acc[g] * yv[g]) - 0.5f;
        }
    }
    __syncthreads();
    int c = tid & 63, chunk = tid >> 6;
    float w20 = weights2[0], w21 = weights2[1];
    float acc2[2][4] = {{0,0,0,0},{0,0,0,0}};
    for (int side = 0; side < 2; ++side) {
        const float* pT = partT + (size_t)(side * T_ + t) * SD_ * C_;
        for (int sd = chunk * 144; sd < (chunk + 1) * 144; ++sd) {
            float pv = pT[sd * C_ + c];
            #pragma unroll
            for (int g = 0; g < 4; ++g) acc2[side][g] += pv * wsd[side][g][sd];
        }
    }
    #pragma unroll
    for (int g = 0; g < 4; ++g) red[tid][g] = acc2[0][g] * w20 + acc2[1][g] * w21;
    __syncthreads();
    if (tid < 64) {
        #pragma unroll
        for (int g = 0; g < 4; ++g) {
            float featv = red[tid][g] + red[tid + 64][g] + red[tid + 128][g] + red[tid + 192][g];
            int thw = base + g;
            float a = 0.f;
            #pragma unroll
            for (int r = 0; r < RC_; ++r) a += w_back[tid * RC_ + r] * agg0[r * THW_ + thw];
            out[tid * THW_ + thw] = featv * (sigm(a) - 0.5f);
        }
    }
}

extern "C" void kernel_launch(void* const* d_in, const int* in_sizes, int n_in,
                              void* d_out, int out_size, void* d_ws, size_t ws_size,
                              hipStream_t stream) {
    const float* x       = (const float*)d_in[0];
    const float* w_dc2   = (const float*)d_in[1];
    const float* w_ofs_l = (const float*)d_in[2];
    const float* b_ofs_l = (const float*)d_in[3];
    const float* w_ofs_r = (const float*)d_in[4];
    const float* b_ofs_r = (const float*)d_in[5];
    const float* ca_w1   = (const float*)d_in[6];
    const float* ca_w2   = (const float*)d_in[7];
    const float* w_down  = (const float*)d_in[8];
    const float* sa1_w   = (const float*)d_in[9];
    const float* sa1_b   = (const float*)d_in[10];
    const float* sa2_w   = (const float*)d_in[11];
    const float* sa2_b   = (const float*)d_in[12];
    const float* sa3_w   = (const float*)d_in[13];
    const float* sa3_b   = (const float*)d_in[14];
    const float* weights = (const float*)d_in[15];
    const float* weights2= (const float*)d_in[16];
    const float* w_back  = (const float*)d_in[17];
    float* out = (float*)d_out;   // OUTPUT IS FLOAT32 (probe-verified round 4)

    // f32 workspace layout (~21.4 MB)
    float* ws    = (float*)d_ws;
    float* x2    = ws;                           // CTHW_
    float* off   = x2 + CTHW_;                   // 36,864
    float* part  = off + 2 * T_ * 2 * SD_;       // 1,179,648
    float* partT = part + 2 * T_ * C_ * SD_;     // 1,179,648
    float* stats = partT + 2 * T_ * C_ * SD_;    // 221,184
    float* yb    = stats + 2 * 3 * THW_;         // 73,728
    float* xd    = yb + 2 * THW_;                // 147,456
    float* agg0  = xd + RC_ * THW_;              // 147,456

    k_x2<<<CTHW_ / 256, 256, 0, stream>>>(x, w_dc2, x2);
    k_off<<<(2 * T_ * 2 * H2_ * W2_) / 256, 256, 0, stream>>>(x, x2, w_ofs_l, b_ofs_l,
                                                              w_ofs_r, b_ofs_r, off);
    k_gs<<<(2 * T_ * SD_) / 256, 256, 0, stream>>>(x2, off, part, partT);
    k_stats<<<(2 * T_ * SD_) / 4, 256, 0, stream>>>(x, part, stats);
    k_attn<<<(2 * THW_) / 256, 256, 0, stream>>>(stats, ca_w1, ca_w2, yb);
    k_xd<<<(RC_ * THW_) / 256, 256, 0, stream>>>(x, w_down, xd);
    k_agg<<<(RC_ * THW_) / 256, 256, 0, stream>>>(xd, sa1_w, sa1_b, sa2_w, sa2_b,
                                                  sa3_w, sa3_b, weights, agg0);
    k_final2<<<T_ * (HW_ / 4), 256, 0, stream>>>(x, part, partT, yb, weights2, agg0, w_back, out);
}

// Round 6
// 874.801 us; speedup vs baseline: 4.4995x; 4.4995x over previous
//
#include <hip/hip_runtime.h>
#include <hip/hip_bf16.h>

#define T_    16
#define C_    64
#define H_    48
#define W_    48
#define HW_   2304
#define THW_  36864
#define CTHW_ 2359296
#define H2_   24
#define W2_   24
#define SD_   576
#define RC_   4

__device__ __forceinline__ float sigm(float v) { return 1.f / (1.f + __expf(-v)); }

// ---------------- x2 = w_dc2 @ x : LDS-tiled, 64thw x 64o per block ----------------
__global__ __launch_bounds__(256) void k_x2(const float* __restrict__ x,
                                            const float* __restrict__ w,
                                            float* __restrict__ x2) {
    int base = blockIdx.x * 64;
    __shared__ float wl[4096];   // [o][c]
    __shared__ float xt[4096];   // [c][u]
    int tid = threadIdx.x;
    for (int i = tid; i < 4096; i += 256) wl[i] = w[i];
    for (int i = tid; i < 4096; i += 256) {
        int c = i >> 6, u = i & 63;
        xt[i] = x[c * THW_ + base + u];
    }
    __syncthreads();
    int o_grp = tid >> 4, u_grp = tid & 15;
    float acc[4][4] = {};
    const float4* xt4 = (const float4*)xt;
    for (int c = 0; c < 64; ++c) {
        float xa[4];
        *(float4*)xa = xt4[c * 16 + u_grp];
        #pragma unroll
        for (int i = 0; i < 4; ++i) {
            float wv = wl[(o_grp * 4 + i) * 64 + c];
            #pragma unroll
            for (int g = 0; g < 4; ++g) acc[i][g] += wv * xa[g];
        }
    }
    #pragma unroll
    for (int i = 0; i < 4; ++i)
        *(float4*)&x2[(o_grp * 4 + i) * THW_ + base + u_grp * 4] = *(float4*)acc[i];
}

// ---------------- offset convs: 3x3 stride2 pad1 over (x + shifted x2) ----------------
__global__ void k_off(const float* __restrict__ x, const float* __restrict__ x2,
                      const float* __restrict__ w_l, const float* __restrict__ b_l,
                      const float* __restrict__ w_r, const float* __restrict__ b_r,
                      float* __restrict__ off) {
    int idx = blockIdx.x * 256 + threadIdx.x;
    if (idx >= 2 * T_ * 2 * H2_ * W2_) return;
    int j = idx % W2_;
    int i = (idx / W2_) % H2_;
    int o = (idx / (W2_ * H2_)) % 2;
    int t = (idx / (W2_ * H2_ * 2)) % T_;
    int side = idx / (W2_ * H2_ * 2 * T_);
    int ts = (side == 0) ? min(t + 1, T_ - 1) : max(t - 1, 0);
    const float* wgt = ((side == 0) ? w_l : w_r) + o * C_ * 9;
    float acc = ((side == 0) ? b_l : b_r)[o];
    for (int c = 0; c < C_; ++c) {
        const float* xc = x + c * THW_ + t * HW_;
        const float* x2c = x2 + c * THW_ + ts * HW_;
        for (int ki = 0; ki < 3; ++ki) {
            int hh = 2 * i - 1 + ki;
            if (hh < 0 || hh >= H_) continue;
            for (int kj = 0; kj < 3; ++kj) {
                int ww = 2 * j - 1 + kj;
                if (ww < 0 || ww >= W_) continue;
                float v = xc[hh * W_ + ww] + x2c[hh * W_ + ww];
                acc += v * wgt[c * 9 + ki * 3 + kj];
            }
        }
    }
    off[idx] = acc;
}

// ---------------- grid sample (bilinear, zeros padding) ----------
// part: [side][t][c][sd]
__global__ void k_gs(const float* __restrict__ x2, const float* __restrict__ off,
                     float* __restrict__ part) {
    int idx = blockIdx.x * 256 + threadIdx.x;
    if (idx >= 2 * T_ * SD_) return;
    int d = idx % W2_;
    int s = (idx / W2_) % H2_;
    int t = (idx / SD_) % T_;
    int side = idx / (SD_ * T_);
    int sd = s * W2_ + d;
    const float* offp = off + (side * T_ + t) * 2 * SD_;
    float v0 = 2.f * (float)d + offp[sd];
    float v1 = 2.f * (float)s + offp[SD_ + sd];
    float xf = 48.f * v0 / 23.f - 0.5f;
    float yf = 48.f * v1 / 23.f - 0.5f;
    float x0 = floorf(xf), y0 = floorf(yf);
    int ix0 = (int)x0, iy0 = (int)y0;
    float fx = xf - x0, fy = yf - y0;
    float w00 = (1.f - fx) * (1.f - fy), w10 = fx * (1.f - fy);
    float w01 = (1.f - fx) * fy,         w11 = fx * fy;
    bool vx0 = (ix0 >= 0 && ix0 < W_), vx1 = (ix0 + 1 >= 0 && ix0 + 1 < W_);
    bool vy0 = (iy0 >= 0 && iy0 < H_), vy1 = (iy0 + 1 >= 0 && iy0 + 1 < H_);
    int cx0 = min(max(ix0, 0), W_ - 1), cx1 = min(max(ix0 + 1, 0), W_ - 1);
    int cy0 = min(max(iy0, 0), H_ - 1), cy1 = min(max(iy0 + 1, 0), H_ - 1);
    float m00 = (vx0 && vy0) ? w00 : 0.f;
    float m10 = (vx1 && vy0) ? w10 : 0.f;
    float m01 = (vx0 && vy1) ? w01 : 0.f;
    float m11 = (vx1 && vy1) ? w11 : 0.f;
    int ts = (side == 0) ? min(t + 1, T_ - 1) : max(t - 1, 0);
    int i00 = cy0 * W_ + cx0, i10 = cy0 * W_ + cx1, i01 = cy1 * W_ + cx0, i11 = cy1 * W_ + cx1;
    for (int c = 0; c < C_; ++c) {
        const float* img = x2 + c * THW_ + ts * HW_;
        part[((size_t)(side * T_ + t) * C_ + c) * SD_ + sd] =
            m00 * img[i00] + m10 * img[i10] + m01 * img[i01] + m11 * img[i11];
    }
}

// ---------------- stats: LDS-tiled aff GEMM, row stats over sd ----------------
// grid: side(2) x t(16) x hw-tile(36); block 256; each thread 4hw x 4sd register tile
__global__ __launch_bounds__(256) void k_stats(const float* __restrict__ x,
                                               const float* __restrict__ part,
                                               float* __restrict__ stats) {
    int bid = blockIdx.x;
    int side = bid / (T_ * 36);
    int rem = bid % (T_ * 36);
    int t = rem / 36, hwt = rem % 36;
    int base = t * HW_ + hwt * 64;
    __shared__ float xs[4096];   // [c][hw]
    __shared__ float ps[4096];   // [c][sd]
    int tid = threadIdx.x;
    for (int i = tid; i < 4096; i += 256) {
        int c = i >> 6, hw = i & 63;
        xs[i] = x[c * THW_ + base + hw];
    }
    const float* pslab = part + (size_t)(side * T_ + t) * C_ * SD_;
    int hw_grp = tid >> 4, sd_grp = tid & 15;
    float sum[4] = {0,0,0,0}, sq[4] = {0,0,0,0};
    float mx[4] = {-1e30f,-1e30f,-1e30f,-1e30f};
    const float4* xs4 = (const float4*)xs;
    const float4* ps4 = (const float4*)ps;
    for (int kt = 0; kt < 9; ++kt) {
        __syncthreads();
        for (int i = tid; i < 4096; i += 256) {
            int c = i >> 6, j = i & 63;
            ps[i] = pslab[c * SD_ + kt * 64 + j];
        }
        __syncthreads();
        float acc[4][4] = {};
        for (int c = 0; c < 64; ++c) {
            float xa[4], pa[4];
            *(float4*)xa = xs4[c * 16 + hw_grp];
            *(float4*)pa = ps4[c * 16 + sd_grp];
            #pragma unroll
            for (int g = 0; g < 4; ++g)
                #pragma unroll
                for (int j = 0; j < 4; ++j) acc[g][j] += xa[g] * pa[j];
        }
        #pragma unroll
        for (int g = 0; g < 4; ++g)
            #pragma unroll
            for (int j = 0; j < 4; ++j) {
                float a = acc[g][j];
                sum[g] += a; sq[g] += a * a; mx[g] = fmaxf(mx[g], a);
            }
    }
    #pragma unroll
    for (int m = 1; m < 16; m <<= 1)
        #pragma unroll
        for (int g = 0; g < 4; ++g) {
            sum[g] += __shfl_xor(sum[g], m);
            sq[g]  += __shfl_xor(sq[g], m);
            mx[g]   = fmaxf(mx[g], __shfl_xor(mx[g], m));
        }
    if (sd_grp == 0) {
        #pragma unroll
        for (int g = 0; g < 4; ++g) {
            int thw = base + hw_grp * 4 + g;
            stats[(side * 3 + 0) * THW_ + thw] = sum[g] * (1.f / 576.f);
            stats[(side * 3 + 1) * THW_ + thw] = mx[g];
            stats[(side * 3 + 2) * THW_ + thw] = (sq[g] - sum[g] * sum[g] * (1.f / 576.f)) * (1.f / 575.f);
        }
    }
}

// ---------------- y = sigmoid(conv3x3([avg,mx],w1) + conv3x3(var,w2)) --------
__global__ void k_attn(const float* __restrict__ stats, const float* __restrict__ ca_w1,
                       const float* __restrict__ ca_w2, float* __restrict__ yb) {
    int idx = blockIdx.x * 256 + threadIdx.x;
    if (idx >= 2 * THW_) return;
    int side = idx / THW_, thw = idx % THW_;
    int w = thw % W_, h = (thw / W_) % H_, t = thw / HW_;
    const float* avg = stats + (side * 3 + 0) * THW_ + t * HW_;
    const float* mxp = stats + (side * 3 + 1) * THW_ + t * HW_;
    const float* var = stats + (side * 3 + 2) * THW_ + t * HW_;
    float acc = 0.f;
    for (int ki = 0; ki < 3; ++ki) {
        int hh = h - 1 + ki;
        if (hh < 0 || hh >= H_) continue;
        for (int kj = 0; kj < 3; ++kj) {
            int ww = w - 1 + kj;
            if (ww < 0 || ww >= W_) continue;
            int p = hh * W_ + ww;
            int kk = ki * 3 + kj;
            acc += ca_w1[kk] * avg[p] + ca_w1[9 + kk] * mxp[p] + ca_w2[kk] * var[p];
        }
    }
    yb[idx] = sigm(acc);
}

// ---------------- xd = w_down @ x ----------------
__global__ void k_xd(const float* __restrict__ x, const float* __restrict__ w_down,
                     float* __restrict__ xd) {
    int idx = blockIdx.x * 256 + threadIdx.x;
    if (idx >= RC_ * THW_) return;
    int r = idx / THW_, thw = idx % THW_;
    float acc = 0.f;
    #pragma unroll 8
    for (int c = 0; c < C_; ++c) acc += w_down[r * C_ + c] * x[c * THW_ + thw];
    xd[idx] = acc;
}

// ---------------- agg0 = sum_i weights[i] * dwconv3d_i(xd) ----------------
__global__ void k_agg(const float* __restrict__ xd,
                      const float* __restrict__ w1, const float* __restrict__ b1,
                      const float* __restrict__ w2, const float* __restrict__ b2,
                      const float* __restrict__ w3, const float* __restrict__ b3,
                      const float* __restrict__ wts, float* __restrict__ agg0) {
    int idx = blockIdx.x * 256 + threadIdx.x;
    if (idx >= RC_ * THW_) return;
    int w = idx % W_;
    int h = (idx / W_) % H_;
    int t = (idx / HW_) % T_;
    int r = idx / THW_;
    const float* xr = xd + r * THW_;
    const float* wk_arr[3] = {w1, w2, w3};
    const float* bs_arr[3] = {b1, b2, b3};
    float tot = 0.f;
    for (int m = 0; m < 3; ++m) {
        int dil = m + 1;
        float acc = bs_arr[m][r];
        const float* wk = wk_arr[m] + r * 81;
        for (int kt = 0; kt < 9; ++kt) {
            int tt = t - 4 + kt;
            if (tt < 0 || tt >= T_) continue;
            for (int kh = 0; kh < 3; ++kh) {
                int hh = h + (kh - 1) * dil;
                if (hh < 0 || hh >= H_) continue;
                for (int kw = 0; kw < 3; ++kw) {
                    int wwp = w + (kw - 1) * dil;
                    if (wwp < 0 || wwp >= W_) continue;
                    acc += xr[tt * HW_ + hh * W_ + wwp] * wk[kt * 9 + kh * 3 + kw];
                }
            }
        }
        tot += acc * wts[m];
    }
    agg0[idx] = tot;
}

// ---------------- final: tiled aff->weight->PV GEMM, both sides, fused gate ----------
// grid: t(16) x hw-tile(36); block 256
__global__ __launch_bounds__(256) void k_final(const float* __restrict__ x,
                                               const float* __restrict__ part,
                                               const float* __restrict__ yb,
                                               const float* __restrict__ weights2,
                                               const float* __restrict__ agg0,
                                               const float* __restrict__ w_back,
                                               float* __restrict__ out) {
    int bid = blockIdx.x;
    int t = bid / 36, hwt = bid % 36;
    int base = t * HW_ + hwt * 64;
    __shared__ float xs[4096];   // [c][hw]
    __shared__ float ps[4096];   // [c][sd]
    __shared__ float wt[4096];   // [hw][sd]
    int tid = threadIdx.x;
    for (int i = tid; i < 4096; i += 256) {
        int c = i >> 6, hw = i & 63;
        xs[i] = x[c * THW_ + base + hw];
    }
    int hw_grpA = tid >> 4, sd_grp = tid & 15;   // phase A roles
    int c_grp = tid >> 4, hw_grpB = tid & 15;    // phase B roles
    const float4* xs4 = (const float4*)xs;
    const float4* ps4 = (const float4*)ps;
    const float4* wt4c = (const float4*)wt;
    float4* wt4 = (float4*)wt;
    float tot[4][4] = {};   // [i over c][g over hw]
    for (int side = 0; side < 2; ++side) {
        const float* pslab = part + (size_t)(side * T_ + t) * C_ * SD_;
        float w2s = weights2[side];
        float yv[4];
        #pragma unroll
        for (int g = 0; g < 4; ++g) yv[g] = yb[side * THW_ + base + hw_grpA * 4 + g];
        float accsd[4][4] = {};
        for (int kt = 0; kt < 9; ++kt) {
            __syncthreads();
            for (int i = tid; i < 4096; i += 256) {
                int c = i >> 6, j = i & 63;
                ps[i] = pslab[c * SD_ + kt * 64 + j];
            }
            __syncthreads();
            // phase A: aff tile + sigmoid weight -> wt LDS
            {
                float acc[4][4] = {};
                for (int c = 0; c < 64; ++c) {
                    float xa[4], pa[4];
                    *(float4*)xa = xs4[c * 16 + hw_grpA];
                    *(float4*)pa = ps4[c * 16 + sd_grp];
                    #pragma unroll
                    for (int g = 0; g < 4; ++g)
                        #pragma unroll
                        for (int j = 0; j < 4; ++j) acc[g][j] += xa[g] * pa[j];
                }
                #pragma unroll
                for (int g = 0; g < 4; ++g) {
                    float w4[4];
                    #pragma unroll
                    for (int j = 0; j < 4; ++j) w4[j] = sigm(acc[g][j] * yv[g]) - 0.5f;
                    wt4[(hw_grpA * 4 + g) * 16 + sd_grp] = *(float4*)w4;
                }
            }
            __syncthreads();
            // phase B: accsd[c][hw] += part[c][sd] * wt[hw][sd]
            for (int j4 = 0; j4 < 16; ++j4) {
                float pa[4][4], wa[4][4];
                #pragma unroll
                for (int i = 0; i < 4; ++i) *(float4*)pa[i] = ps4[(c_grp * 4 + i) * 16 + j4];
                #pragma unroll
                for (int g = 0; g < 4; ++g) *(float4*)wa[g] = wt4c[(hw_grpB * 4 + g) * 16 + j4];
                #pragma unroll
                for (int i = 0; i < 4; ++i)
                    #pragma unroll
                    for (int g = 0; g < 4; ++g)
                        #pragma unroll
                        for (int jj = 0; jj < 4; ++jj) accsd[i][g] += pa[i][jj] * wa[g][jj];
            }
        }
        #pragma unroll
        for (int i = 0; i < 4; ++i)
            #pragma unroll
            for (int g = 0; g < 4; ++g) tot[i][g] += w2s * accsd[i][g];
    }
    // epilogue: gate + store (phase B mapping)
    int c0 = c_grp * 4, hwb = hw_grpB * 4;
    float ag[4][4];
    #pragma unroll
    for (int r = 0; r < RC_; ++r)
        *(float4*)ag[r] = *(const float4*)&agg0[r * THW_ + base + hwb];
    #pragma unroll
    for (int i = 0; i < 4; ++i) {
        float o4[4];
        #pragma unroll
        for (int g = 0; g < 4; ++g) {
            float a = 0.f;
            #pragma unroll
            for (int r = 0; r < RC_; ++r) a += w_back[(c0 + i) * RC_ + r] * ag[r][g];
            o4[g] = tot[i][g] * (sigm(a) - 0.5f);
        }
        *(float4*)&out[(c0 + i) * THW_ + base + hwb] = *(float4*)o4;
    }
}

extern "C" void kernel_launch(void* const* d_in, const int* in_sizes, int n_in,
                              void* d_out, int out_size, void* d_ws, size_t ws_size,
                              hipStream_t stream) {
    const float* x       = (const float*)d_in[0];
    const float* w_dc2   = (const float*)d_in[1];
    const float* w_ofs_l = (const float*)d_in[2];
    const float* b_ofs_l = (const float*)d_in[3];
    const float* w_ofs_r = (const float*)d_in[4];
    const float* b_ofs_r = (const float*)d_in[5];
    const float* ca_w1   = (const float*)d_in[6];
    const float* ca_w2   = (const float*)d_in[7];
    const float* w_down  = (const float*)d_in[8];
    const float* sa1_w   = (const float*)d_in[9];
    const float* sa1_b   = (const float*)d_in[10];
    const float* sa2_w   = (const float*)d_in[11];
    const float* sa2_b   = (const float*)d_in[12];
    const float* sa3_w   = (const float*)d_in[13];
    const float* sa3_b   = (const float*)d_in[14];
    const float* weights = (const float*)d_in[15];
    const float* weights2= (const float*)d_in[16];
    const float* w_back  = (const float*)d_in[17];
    float* out = (float*)d_out;

    // f32 workspace layout (~16.7 MB)
    float* ws    = (float*)d_ws;
    float* x2    = ws;                           // CTHW_
    float* off   = x2 + CTHW_;                   // 36,864
    float* part  = off + 2 * T_ * 2 * SD_;       // 1,179,648
    float* stats = part + 2 * T_ * C_ * SD_;     // 221,184
    float* yb    = stats + 2 * 3 * THW_;         // 73,728
    float* xd    = yb + 2 * THW_;                // 147,456
    float* agg0  = xd + RC_ * THW_;              // 147,456

    k_x2<<<THW_ / 64, 256, 0, stream>>>(x, w_dc2, x2);
    k_off<<<(2 * T_ * 2 * H2_ * W2_) / 256, 256, 0, stream>>>(x, x2, w_ofs_l, b_ofs_l,
                                                              w_ofs_r, b_ofs_r, off);
    k_gs<<<(2 * T_ * SD_) / 256, 256, 0, stream>>>(x2, off, part);
    k_stats<<<2 * T_ * 36, 256, 0, stream>>>(x, part, stats);
    k_attn<<<(2 * THW_) / 256, 256, 0, stream>>>(stats, ca_w1, ca_w2, yb);
    k_xd<<<(RC_ * THW_) / 256, 256, 0, stream>>>(x, w_down, xd);
    k_agg<<<(RC_ * THW_) / 256, 256, 0, stream>>>(xd, sa1_w, sa1_b, sa2_w, sa2_b,
                                                  sa3_w, sa3_b, weights, agg0);
    k_final<<<T_ * 36, 256, 0, stream>>>(x, part, yb, weights2, agg0, w_back, out);
}

// Round 7
// 574.264 us; speedup vs baseline: 6.8543x; 1.5233x over previous
//
#include <hip/hip_runtime.h>
#include <hip/hip_bf16.h>

#define T_    16
#define C_    64
#define H_    48
#define W_    48
#define HW_   2304
#define THW_  36864
#define CTHW_ 2359296
#define H2_   24
#define W2_   24
#define SD_   576
#define RC_   4
#define LP_   68   // padded LDS row stride (floats): bank-quad shift 16/row, 16B aligned
#define LP4_  17   // LP_/4

__device__ __forceinline__ float sigm(float v) { return 1.f / (1.f + __expf(-v)); }

// ---------------- x2 = w_dc2 @ x : LDS-tiled, 64thw x 64o per block ----------------
__global__ __launch_bounds__(256) void k_x2(const float* __restrict__ x,
                                            const float* __restrict__ w,
                                            float* __restrict__ x2) {
    int base = blockIdx.x * 64;
    __shared__ float wl[64 * 65];  // [o][c] padded
    __shared__ float xt[4096];     // [c][u]
    int tid = threadIdx.x;
    for (int i = tid; i < 4096; i += 256) wl[(i >> 6) * 65 + (i & 63)] = w[i];
    for (int i = tid; i < 4096; i += 256) {
        int c = i >> 6, u = i & 63;
        xt[i] = x[c * THW_ + base + u];
    }
    __syncthreads();
    int o_grp = tid >> 4, u_grp = tid & 15;
    float acc[4][4] = {};
    const float4* xt4 = (const float4*)xt;
    for (int c = 0; c < 64; ++c) {
        float xa[4];
        *(float4*)xa = xt4[c * 16 + u_grp];
        #pragma unroll
        for (int i = 0; i < 4; ++i) {
            float wv = wl[(o_grp * 4 + i) * 65 + c];
            #pragma unroll
            for (int g = 0; g < 4; ++g) acc[i][g] += wv * xa[g];
        }
    }
    #pragma unroll
    for (int i = 0; i < 4; ++i)
        *(float4*)&x2[(o_grp * 4 + i) * THW_ + base + u_grp * 4] = *(float4*)acc[i];
}

// ---------------- offset convs: 3x3 stride2 pad1 over (x + shifted x2) ----------------
__global__ void k_off(const float* __restrict__ x, const float* __restrict__ x2,
                      const float* __restrict__ w_l, const float* __restrict__ b_l,
                      const float* __restrict__ w_r, const float* __restrict__ b_r,
                      float* __restrict__ off) {
    int idx = blockIdx.x * 256 + threadIdx.x;
    if (idx >= 2 * T_ * 2 * H2_ * W2_) return;
    int j = idx % W2_;
    int i = (idx / W2_) % H2_;
    int o = (idx / (W2_ * H2_)) % 2;
    int t = (idx / (W2_ * H2_ * 2)) % T_;
    int side = idx / (W2_ * H2_ * 2 * T_);
    int ts = (side == 0) ? min(t + 1, T_ - 1) : max(t - 1, 0);
    const float* wgt = ((side == 0) ? w_l : w_r) + o * C_ * 9;
    float acc = ((side == 0) ? b_l : b_r)[o];
    for (int c = 0; c < C_; ++c) {
        const float* xc = x + c * THW_ + t * HW_;
        const float* x2c = x2 + c * THW_ + ts * HW_;
        for (int ki = 0; ki < 3; ++ki) {
            int hh = 2 * i - 1 + ki;
            if (hh < 0 || hh >= H_) continue;
            for (int kj = 0; kj < 3; ++kj) {
                int ww = 2 * j - 1 + kj;
                if (ww < 0 || ww >= W_) continue;
                float v = xc[hh * W_ + ww] + x2c[hh * W_ + ww];
                acc += v * wgt[c * 9 + ki * 3 + kj];
            }
        }
    }
    off[idx] = acc;
}

// ---------------- grid sample (bilinear, zeros padding); part: [side][t][c][sd] ----------
__global__ void k_gs(const float* __restrict__ x2, const float* __restrict__ off,
                     float* __restrict__ part) {
    int idx = blockIdx.x * 256 + threadIdx.x;
    if (idx >= 2 * T_ * SD_) return;
    int d = idx % W2_;
    int s = (idx / W2_) % H2_;
    int t = (idx / SD_) % T_;
    int side = idx / (SD_ * T_);
    int sd = s * W2_ + d;
    const float* offp = off + (side * T_ + t) * 2 * SD_;
    float v0 = 2.f * (float)d + offp[sd];
    float v1 = 2.f * (float)s + offp[SD_ + sd];
    float xf = 48.f * v0 / 23.f - 0.5f;
    float yf = 48.f * v1 / 23.f - 0.5f;
    float x0 = floorf(xf), y0 = floorf(yf);
    int ix0 = (int)x0, iy0 = (int)y0;
    float fx = xf - x0, fy = yf - y0;
    float w00 = (1.f - fx) * (1.f - fy), w10 = fx * (1.f - fy);
    float w01 = (1.f - fx) * fy,         w11 = fx * fy;
    bool vx0 = (ix0 >= 0 && ix0 < W_), vx1 = (ix0 + 1 >= 0 && ix0 + 1 < W_);
    bool vy0 = (iy0 >= 0 && iy0 < H_), vy1 = (iy0 + 1 >= 0 && iy0 + 1 < H_);
    int cx0 = min(max(ix0, 0), W_ - 1), cx1 = min(max(ix0 + 1, 0), W_ - 1);
    int cy0 = min(max(iy0, 0), H_ - 1), cy1 = min(max(iy0 + 1, 0), H_ - 1);
    float m00 = (vx0 && vy0) ? w00 : 0.f;
    float m10 = (vx1 && vy0) ? w10 : 0.f;
    float m01 = (vx0 && vy1) ? w01 : 0.f;
    float m11 = (vx1 && vy1) ? w11 : 0.f;
    int ts = (side == 0) ? min(t + 1, T_ - 1) : max(t - 1, 0);
    int i00 = cy0 * W_ + cx0, i10 = cy0 * W_ + cx1, i01 = cy1 * W_ + cx0, i11 = cy1 * W_ + cx1;
    for (int c = 0; c < C_; ++c) {
        const float* img = x2 + c * THW_ + ts * HW_;
        part[((size_t)(side * T_ + t) * C_ + c) * SD_ + sd] =
            m00 * img[i00] + m10 * img[i10] + m01 * img[i01] + m11 * img[i11];
    }
}

// ---------------- stats: LDS-tiled aff GEMM (padded), row stats over sd ----------------
__global__ __launch_bounds__(256) void k_stats(const float* __restrict__ x,
                                               const float* __restrict__ part,
                                               float* __restrict__ stats) {
    int bid = blockIdx.x;
    int side = bid / (T_ * 36);
    int rem = bid % (T_ * 36);
    int t = rem / 36, hwt = rem % 36;
    int base = t * HW_ + hwt * 64;
    __shared__ float xs[64 * LP_];
    __shared__ float ps[64 * LP_];
    int tid = threadIdx.x;
    for (int i = tid; i < 4096; i += 256)
        xs[(i >> 6) * LP_ + (i & 63)] = x[(i >> 6) * THW_ + base + (i & 63)];
    const float* pslab = part + (size_t)(side * T_ + t) * C_ * SD_;
    int hw_grp = tid >> 4, sd_grp = tid & 15;
    float sum[4] = {0,0,0,0}, sq[4] = {0,0,0,0};
    float mx[4] = {-1e30f,-1e30f,-1e30f,-1e30f};
    const float4* xs4 = (const float4*)xs;
    const float4* ps4 = (const float4*)ps;
    for (int kt = 0; kt < 9; ++kt) {
        __syncthreads();
        for (int i = tid; i < 4096; i += 256)
            ps[(i >> 6) * LP_ + (i & 63)] = pslab[(i >> 6) * SD_ + kt * 64 + (i & 63)];
        __syncthreads();
        float acc[4][4] = {};
        for (int c = 0; c < 64; ++c) {
            float xa[4], pa[4];
            *(float4*)xa = xs4[c * LP4_ + hw_grp];
            *(float4*)pa = ps4[c * LP4_ + sd_grp];
            #pragma unroll
            for (int g = 0; g < 4; ++g)
                #pragma unroll
                for (int j = 0; j < 4; ++j) acc[g][j] += xa[g] * pa[j];
        }
        #pragma unroll
        for (int g = 0; g < 4; ++g)
            #pragma unroll
            for (int j = 0; j < 4; ++j) {
                float a = acc[g][j];
                sum[g] += a; sq[g] += a * a; mx[g] = fmaxf(mx[g], a);
            }
    }
    #pragma unroll
    for (int m = 1; m < 16; m <<= 1)
        #pragma unroll
        for (int g = 0; g < 4; ++g) {
            sum[g] += __shfl_xor(sum[g], m);
            sq[g]  += __shfl_xor(sq[g], m);
            mx[g]   = fmaxf(mx[g], __shfl_xor(mx[g], m));
        }
    if (sd_grp == 0) {
        #pragma unroll
        for (int g = 0; g < 4; ++g) {
            int thw = base + hw_grp * 4 + g;
            stats[(side * 3 + 0) * THW_ + thw] = sum[g] * (1.f / 576.f);
            stats[(side * 3 + 1) * THW_ + thw] = mx[g];
            stats[(side * 3 + 2) * THW_ + thw] = (sq[g] - sum[g] * sum[g] * (1.f / 576.f)) * (1.f / 575.f);
        }
    }
}

// ---------------- y = sigmoid(conv3x3([avg,mx],w1) + conv3x3(var,w2)) --------
__global__ void k_attn(const float* __restrict__ stats, const float* __restrict__ ca_w1,
                       const float* __restrict__ ca_w2, float* __restrict__ yb) {
    int idx = blockIdx.x * 256 + threadIdx.x;
    if (idx >= 2 * THW_) return;
    int side = idx / THW_, thw = idx % THW_;
    int w = thw % W_, h = (thw / W_) % H_, t = thw / HW_;
    const float* avg = stats + (side * 3 + 0) * THW_ + t * HW_;
    const float* mxp = stats + (side * 3 + 1) * THW_ + t * HW_;
    const float* var = stats + (side * 3 + 2) * THW_ + t * HW_;
    float acc = 0.f;
    for (int ki = 0; ki < 3; ++ki) {
        int hh = h - 1 + ki;
        if (hh < 0 || hh >= H_) continue;
        for (int kj = 0; kj < 3; ++kj) {
            int ww = w - 1 + kj;
            if (ww < 0 || ww >= W_) continue;
            int p = hh * W_ + ww;
            int kk = ki * 3 + kj;
            acc += ca_w1[kk] * avg[p] + ca_w1[9 + kk] * mxp[p] + ca_w2[kk] * var[p];
        }
    }
    yb[idx] = sigm(acc);
}

// ---------------- xd = w_down @ x ----------------
__global__ void k_xd(const float* __restrict__ x, const float* __restrict__ w_down,
                     float* __restrict__ xd) {
    int idx = blockIdx.x * 256 + threadIdx.x;
    if (idx >= RC_ * THW_) return;
    int r = idx / THW_, thw = idx % THW_;
    float acc = 0.f;
    #pragma unroll 8
    for (int c = 0; c < C_; ++c) acc += w_down[r * C_ + c] * x[c * THW_ + thw];
    xd[idx] = acc;
}

// ---------------- agg0 = sum_i weights[i] * dwconv3d_i(xd) ----------------
__global__ void k_agg(const float* __restrict__ xd,
                      const float* __restrict__ w1, const float* __restrict__ b1,
                      const float* __restrict__ w2, const float* __restrict__ b2,
                      const float* __restrict__ w3, const float* __restrict__ b3,
                      const float* __restrict__ wts, float* __restrict__ agg0) {
    int idx = blockIdx.x * 256 + threadIdx.x;
    if (idx >= RC_ * THW_) return;
    int w = idx % W_;
    int h = (idx / W_) % H_;
    int t = (idx / HW_) % T_;
    int r = idx / THW_;
    const float* xr = xd + r * THW_;
    const float* wk_arr[3] = {w1, w2, w3};
    const float* bs_arr[3] = {b1, b2, b3};
    float tot = 0.f;
    for (int m = 0; m < 3; ++m) {
        int dil = m + 1;
        float acc = bs_arr[m][r];
        const float* wk = wk_arr[m] + r * 81;
        for (int kt = 0; kt < 9; ++kt) {
            int tt = t - 4 + kt;
            if (tt < 0 || tt >= T_) continue;
            for (int kh = 0; kh < 3; ++kh) {
                int hh = h + (kh - 1) * dil;
                if (hh < 0 || hh >= H_) continue;
                for (int kw = 0; kw < 3; ++kw) {
                    int wwp = w + (kw - 1) * dil;
                    if (wwp < 0 || wwp >= W_) continue;
                    acc += xr[tt * HW_ + hh * W_ + wwp] * wk[kt * 9 + kh * 3 + kw];
                }
            }
        }
        tot += acc * wts[m];
    }
    agg0[idx] = tot;
}

// ---------------- final: per-side tiled aff->weight->PV GEMM, padded LDS ----------
// grid: side(2) x t(16) x hw-tile(36); block 256
// phase B lane map: lane = hw (spread wt reads, coalesced stores); wave = 16-c chunk
__global__ __launch_bounds__(256) void k_final(const float* __restrict__ x,
                                               const float* __restrict__ part,
                                               const float* __restrict__ yb,
                                               const float* __restrict__ weights2,
                                               float* __restrict__ featP) {
    int bid = blockIdx.x;
    int side = bid / (T_ * 36);
    int rem = bid % (T_ * 36);
    int t = rem / 36, hwt = rem % 36;
    int base = t * HW_ + hwt * 64;
    __shared__ float xs[64 * LP_];
    __shared__ float ps[64 * LP_];
    __shared__ float wt[64 * LP_];   // [hw][sd]
    int tid = threadIdx.x;
    for (int i = tid; i < 4096; i += 256)
        xs[(i >> 6) * LP_ + (i & 63)] = x[(i >> 6) * THW_ + base + (i & 63)];
    int hw_grpA = tid >> 4, sd_grp = tid & 15;   // phase A roles
    int hwB = tid & 63, wv = tid >> 6;           // phase B roles
    const float4* xs4 = (const float4*)xs;
    const float4* ps4 = (const float4*)ps;
    const float4* wt4c = (const float4*)wt;
    float4* wt4 = (float4*)wt;
    const float* pslab = part + (size_t)(side * T_ + t) * C_ * SD_;
    float yv[4];
    #pragma unroll
    for (int g = 0; g < 4; ++g) yv[g] = yb[side * THW_ + base + hw_grpA * 4 + g];
    float accB[16] = {};
    for (int kt = 0; kt < 9; ++kt) {
        __syncthreads();
        for (int i = tid; i < 4096; i += 256)
            ps[(i >> 6) * LP_ + (i & 63)] = pslab[(i >> 6) * SD_ + kt * 64 + (i & 63)];
        __syncthreads();
        // phase A: aff tile + sigmoid weight -> wt
        {
            float acc[4][4] = {};
            for (int c = 0; c < 64; ++c) {
                float xa[4], pa[4];
                *(float4*)xa = xs4[c * LP4_ + hw_grpA];
                *(float4*)pa = ps4[c * LP4_ + sd_grp];
                #pragma unroll
                for (int g = 0; g < 4; ++g)
                    #pragma unroll
                    for (int j = 0; j < 4; ++j) acc[g][j] += xa[g] * pa[j];
            }
            #pragma unroll
            for (int g = 0; g < 4; ++g) {
                float w4[4];
                #pragma unroll
                for (int j = 0; j < 4; ++j) w4[j] = sigm(acc[g][j] * yv[g]) - 0.5f;
                wt4[(hw_grpA * 4 + g) * LP4_ + sd_grp] = *(float4*)w4;
            }
        }
        __syncthreads();
        // phase B: accB[k over c] += ps[c][sd] * wt[hwB][sd]
        for (int sd4 = 0; sd4 < 16; ++sd4) {
            float wa[4];
            *(float4*)wa = wt4c[hwB * LP4_ + sd4];     // spread over 64 hw rows
            #pragma unroll
            for (int k = 0; k < 16; ++k) {
                float pa[4];
                *(float4*)pa = ps4[(wv * 16 + k) * LP4_ + sd4];  // wave-uniform broadcast
                #pragma unroll
                for (int jj = 0; jj < 4; ++jj) accB[k] += pa[jj] * wa[jj];
            }
        }
    }
    float w2s = weights2[side];
    #pragma unroll
    for (int k = 0; k < 16; ++k)
        featP[(size_t)side * CTHW_ + (wv * 16 + k) * THW_ + base + hwB] = accB[k] * w2s;
}

// ---------------- epilogue: out = (featP0+featP1) * (sigm(w_back@agg0)-0.5) ----------
__global__ void k_out(const float* __restrict__ featP, const float* __restrict__ agg0,
                      const float* __restrict__ w_back, float* __restrict__ out) {
    int idx = blockIdx.x * 256 + threadIdx.x;
    if (idx >= CTHW_) return;
    int o = idx / THW_, thw = idx % THW_;
    float a = 0.f;
    #pragma unroll
    for (int r = 0; r < RC_; ++r) a += w_back[o * RC_ + r] * agg0[r * THW_ + thw];
    out[idx] = (featP[idx] + featP[CTHW_ + idx]) * (sigm(a) - 0.5f);
}

extern "C" void kernel_launch(void* const* d_in, const int* in_sizes, int n_in,
                              void* d_out, int out_size, void* d_ws, size_t ws_size,
                              hipStream_t stream) {
    const float* x       = (const float*)d_in[0];
    const float* w_dc2   = (const float*)d_in[1];
    const float* w_ofs_l = (const float*)d_in[2];
    const float* b_ofs_l = (const float*)d_in[3];
    const float* w_ofs_r = (const float*)d_in[4];
    const float* b_ofs_r = (const float*)d_in[5];
    const float* ca_w1   = (const float*)d_in[6];
    const float* ca_w2   = (const float*)d_in[7];
    const float* w_down  = (const float*)d_in[8];
    const float* sa1_w   = (const float*)d_in[9];
    const float* sa1_b   = (const float*)d_in[10];
    const float* sa2_w   = (const float*)d_in[11];
    const float* sa2_b   = (const float*)d_in[12];
    const float* sa3_w   = (const float*)d_in[13];
    const float* sa3_b   = (const float*)d_in[14];
    const float* weights = (const float*)d_in[15];
    const float* weights2= (const float*)d_in[16];
    const float* w_back  = (const float*)d_in[17];
    float* out = (float*)d_out;

    // f32 workspace (~26.1 MB). featP[0] overlays x2 (dead after k_gs).
    float* ws    = (float*)d_ws;
    float* x2    = ws;                           // CTHW_  -> becomes featP side 0
    float* featP = x2;                           // [2][CTHW_]
    float* off   = featP + 2 * CTHW_;            // 36,864
    float* part  = off + 2 * T_ * 2 * SD_;       // 1,179,648
    float* stats = part + 2 * T_ * C_ * SD_;     // 221,184
    float* yb    = stats + 2 * 3 * THW_;         // 73,728
    float* xd    = yb + 2 * THW_;                // 147,456
    float* agg0  = xd + RC_ * THW_;              // 147,456

    k_x2<<<THW_ / 64, 256, 0, stream>>>(x, w_dc2, x2);
    k_off<<<(2 * T_ * 2 * H2_ * W2_) / 256, 256, 0, stream>>>(x, x2, w_ofs_l, b_ofs_l,
                                                              w_ofs_r, b_ofs_r, off);
    k_gs<<<(2 * T_ * SD_) / 256, 256, 0, stream>>>(x2, off, part);
    k_stats<<<2 * T_ * 36, 256, 0, stream>>>(x, part, stats);
    k_attn<<<(2 * THW_) / 256, 256, 0, stream>>>(stats, ca_w1, ca_w2, yb);
    k_xd<<<(RC_ * THW_) / 256, 256, 0, stream>>>(x, w_down, xd);
    k_agg<<<(RC_ * THW_) / 256, 256, 0, stream>>>(xd, sa1_w, sa1_b, sa2_w, sa2_b,
                                                  sa3_w, sa3_b, weights, agg0);
    k_final<<<2 * T_ * 36, 256, 0, stream>>>(x, part, yb, weights2, featP);
    k_out<<<CTHW_ / 256, 256, 0, stream>>>(featP, agg0, w_back, out);
}

// Round 9
// 513.319 us; speedup vs baseline: 7.6681x; 1.1187x over previous
//
#include <hip/hip_runtime.h>

#define T_    16
#define C_    64
#define H_    48
#define W_    48
#define HW_   2304
#define THW_  36864
#define CTHW_ 2359296
#define H2_   24
#define W2_   24
#define SD_   576
#define RC_   4
#define LP_   68   // padded LDS row stride (floats)
#define LP4_  17   // LP_/4

__device__ __forceinline__ float sigm(float v) { return 1.f / (1.f + __expf(-v)); }

// ---------------- k_x2: x2 = w_dc2 @ x, channel-last x2T[thw][o] ----------------
__global__ __launch_bounds__(256) void k_x2(const float* __restrict__ x,
                                            const float* __restrict__ w,
                                            float* __restrict__ x2T) {
    int base = blockIdx.x * 64;
    __shared__ float wl[64 * 65];  // [o][c] padded
    __shared__ float xt[4096];     // [c][u]
    int tid = threadIdx.x;
    for (int i = tid; i < 4096; i += 256) wl[(i >> 6) * 65 + (i & 63)] = w[i];
    for (int i = tid; i < 4096; i += 256) xt[i] = x[(i >> 6) * THW_ + base + (i & 63)];
    __syncthreads();
    int o_grp = tid >> 4, u_grp = tid & 15;
    float acc[4][4] = {};
    const float4* xt4 = (const float4*)xt;
    for (int c = 0; c < 64; ++c) {
        float xa[4];
        *(float4*)xa = xt4[c * 16 + u_grp];
        #pragma unroll
        for (int i = 0; i < 4; ++i) {
            float wv = wl[(o_grp * 4 + i) * 65 + c];
            #pragma unroll
            for (int g = 0; g < 4; ++g) acc[i][g] += wv * xa[g];
        }
    }
    #pragma unroll
    for (int g = 0; g < 4; ++g) {
        float4 v = make_float4(acc[0][g], acc[1][g], acc[2][g], acc[3][g]);
        *(float4*)&x2T[(size_t)(base + u_grp * 4 + g) * 64 + o_grp * 4] = v;
    }
}

// ---------------- k_off: wave per (side,t,i,j), lane = channel ----------------
// off layout: [side][t][o(2)][i(24)][j(24)]
__global__ __launch_bounds__(256) void k_off(const float* __restrict__ x,
                                             const float* __restrict__ x2T,
                                             const float* __restrict__ w_l,
                                             const float* __restrict__ b_l,
                                             const float* __restrict__ w_r,
                                             const float* __restrict__ b_r,
                                             float* __restrict__ off) {
    __shared__ float wlds[2304];   // w_l (1152) then w_r (1152), [o][c][tap]
    int tid = threadIdx.x;
    for (int i = tid; i < 2304; i += 256) wlds[i] = (i < 1152) ? w_l[i] : w_r[i - 1152];
    __syncthreads();
    int wg = blockIdx.x * 4 + (tid >> 6);
    int lane = tid & 63;
    int j = wg % 24, i = (wg / 24) % 24, t = (wg / 576) % 16, side = wg / 9216;
    int ts = (side == 0) ? min(t + 1, T_ - 1) : max(t - 1, 0);
    const float* wp = wlds + side * 1152;
    const float* xl = x + (size_t)lane * THW_ + t * HW_;
    const float* x2l = x2T + (size_t)ts * HW_ * 64 + lane;
    float a0 = 0.f, a1 = 0.f;
    for (int ki = 0; ki < 3; ++ki) {
        int hh = 2 * i - 1 + ki;
        if (hh < 0 || hh >= H_) continue;
        for (int kj = 0; kj < 3; ++kj) {
            int ww = 2 * j - 1 + kj;
            if (ww < 0 || ww >= W_) continue;
            int pos = hh * W_ + ww;
            float s = xl[pos] + x2l[(size_t)pos * 64];
            int tap = ki * 3 + kj;
            a0 += s * wp[lane * 9 + tap];
            a1 += s * wp[576 + lane * 9 + tap];
        }
    }
    #pragma unroll
    for (int m = 32; m >= 1; m >>= 1) {
        a0 += __shfl_xor(a0, m);
        a1 += __shfl_xor(a1, m);
    }
    if (lane == 0) {
        const float* bb = (side == 0) ? b_l : b_r;
        int ob = (side * 16 + t) * 1152 + i * 24 + j;
        off[ob] = a0 + bb[0];
        off[ob + 576] = a1 + bb[1];
    }
}

// ---------------- k_gs: wave per (side,t,sd), lane = channel; partC[st][sd][c] -----
__global__ __launch_bounds__(256) void k_gs(const float* __restrict__ x2T,
                                            const float* __restrict__ off,
                                            float* __restrict__ partC) {
    int wg = blockIdx.x * 4 + (threadIdx.x >> 6);
    int lane = threadIdx.x & 63;
    int sd = wg % 576;
    int t = (wg / 576) % 16;
    int side = wg / 9216;
    int d = sd % W2_, s = sd / W2_;
    const float* offp = off + (side * 16 + t) * 1152;
    float v0 = 2.f * (float)d + offp[sd];
    float v1 = 2.f * (float)s + offp[576 + sd];
    float xf = 48.f * v0 / 23.f - 0.5f;
    float yf = 48.f * v1 / 23.f - 0.5f;
    float x0 = floorf(xf), y0 = floorf(yf);
    int ix0 = (int)x0, iy0 = (int)y0;
    float fx = xf - x0, fy = yf - y0;
    float w00 = (1.f - fx) * (1.f - fy), w10 = fx * (1.f - fy);
    float w01 = (1.f - fx) * fy,         w11 = fx * fy;
    bool vx0 = (ix0 >= 0 && ix0 < W_), vx1 = (ix0 + 1 >= 0 && ix0 + 1 < W_);
    bool vy0 = (iy0 >= 0 && iy0 < H_), vy1 = (iy0 + 1 >= 0 && iy0 + 1 < H_);
    int cx0 = min(max(ix0, 0), W_ - 1), cx1 = min(max(ix0 + 1, 0), W_ - 1);
    int cy0 = min(max(iy0, 0), H_ - 1), cy1 = min(max(iy0 + 1, 0), H_ - 1);
    float m00 = (vx0 && vy0) ? w00 : 0.f;
    float m10 = (vx1 && vy0) ? w10 : 0.f;
    float m01 = (vx0 && vy1) ? w01 : 0.f;
    float m11 = (vx1 && vy1) ? w11 : 0.f;
    int ts = (side == 0) ? min(t + 1, T_ - 1) : max(t - 1, 0);
    const float* img = x2T + (size_t)ts * HW_ * 64;
    float val = m00 * img[(size_t)(cy0 * W_ + cx0) * 64 + lane]
              + m10 * img[(size_t)(cy0 * W_ + cx1) * 64 + lane]
              + m01 * img[(size_t)(cy1 * W_ + cx0) * 64 + lane]
              + m11 * img[(size_t)(cy1 * W_ + cx1) * 64 + lane];
    partC[((size_t)(side * 16 + t) * 576 + sd) * 64 + lane] = val;
}

// ---------------- k_tr: transpose partC [st][sd][c] -> part [st][c][sd] ----------
__global__ __launch_bounds__(256) void k_tr(const float* __restrict__ partC,
                                            float* __restrict__ part) {
    int st = blockIdx.x / 9;
    int sdt = blockIdx.x % 9;
    __shared__ float ld[64 * 65];
    int tid = threadIdx.x;
    const float* src = partC + ((size_t)st * 576 + sdt * 64) * 64;
    for (int i = tid; i < 4096; i += 256) ld[(i >> 6) * 65 + (i & 63)] = src[i];
    __syncthreads();
    float* dst = part + (size_t)st * 64 * 576 + sdt * 64;
    for (int i = tid; i < 4096; i += 256) {
        int c = i >> 6, sdl = i & 63;
        dst[c * 576 + sdl] = ld[sdl * 65 + c];
    }
}

// ---------------- k_stats (round-7 verbatim): LDS-tiled aff GEMM, stats over sd ------
__global__ __launch_bounds__(256) void k_stats(const float* __restrict__ x,
                                               const float* __restrict__ part,
                                               float* __restrict__ stats) {
    int bid = blockIdx.x;
    int side = bid / (T_ * 36);
    int rem = bid % (T_ * 36);
    int t = rem / 36, hwt = rem % 36;
    int base = t * HW_ + hwt * 64;
    __shared__ float xs[64 * LP_];
    __shared__ float ps[64 * LP_];
    int tid = threadIdx.x;
    for (int i = tid; i < 4096; i += 256)
        xs[(i >> 6) * LP_ + (i & 63)] = x[(i >> 6) * THW_ + base + (i & 63)];
    const float* pslab = part + (size_t)(side * T_ + t) * C_ * SD_;
    int hw_grp = tid >> 4, sd_grp = tid & 15;
    float sum[4] = {0,0,0,0}, sq[4] = {0,0,0,0};
    float mx[4] = {-1e30f,-1e30f,-1e30f,-1e30f};
    const float4* xs4 = (const float4*)xs;
    const float4* ps4 = (const float4*)ps;
    for (int kt = 0; kt < 9; ++kt) {
        __syncthreads();
        for (int i = tid; i < 4096; i += 256)
            ps[(i >> 6) * LP_ + (i & 63)] = pslab[(i >> 6) * SD_ + kt * 64 + (i & 63)];
        __syncthreads();
        float acc[4][4] = {};
        for (int c = 0; c < 64; ++c) {
            float xa[4], pa[4];
            *(float4*)xa = xs4[c * LP4_ + hw_grp];
            *(float4*)pa = ps4[c * LP4_ + sd_grp];
            #pragma unroll
            for (int g = 0; g < 4; ++g)
                #pragma unroll
                for (int j = 0; j < 4; ++j) acc[g][j] += xa[g] * pa[j];
        }
        #pragma unroll
        for (int g = 0; g < 4; ++g)
            #pragma unroll
            for (int j = 0; j < 4; ++j) {
                float a = acc[g][j];
                sum[g] += a; sq[g] += a * a; mx[g] = fmaxf(mx[g], a);
            }
    }
    #pragma unroll
    for (int m = 1; m < 16; m <<= 1)
        #pragma unroll
        for (int g = 0; g < 4; ++g) {
            sum[g] += __shfl_xor(sum[g], m);
            sq[g]  += __shfl_xor(sq[g], m);
            mx[g]   = fmaxf(mx[g], __shfl_xor(mx[g], m));
        }
    if (sd_grp == 0) {
        #pragma unroll
        for (int g = 0; g < 4; ++g) {
            int thw = base + hw_grp * 4 + g;
            stats[(side * 3 + 0) * THW_ + thw] = sum[g] * (1.f / 576.f);
            stats[(side * 3 + 1) * THW_ + thw] = mx[g];
            stats[(side * 3 + 2) * THW_ + thw] = (sq[g] - sum[g] * sum[g] * (1.f / 576.f)) * (1.f / 575.f);
        }
    }
}

// ---------------- y = sigmoid(conv3x3([avg,mx],w1) + conv3x3(var,w2)) --------
__global__ void k_attn(const float* __restrict__ stats, const float* __restrict__ ca_w1,
                       const float* __restrict__ ca_w2, float* __restrict__ yb) {
    int idx = blockIdx.x * 256 + threadIdx.x;
    if (idx >= 2 * THW_) return;
    int side = idx / THW_, thw = idx % THW_;
    int w = thw % W_, h = (thw / W_) % H_, t = thw / HW_;
    const float* avg = stats + (side * 3 + 0) * THW_ + t * HW_;
    const float* mxp = stats + (side * 3 + 1) * THW_ + t * HW_;
    const float* var = stats + (side * 3 + 2) * THW_ + t * HW_;
    float acc = 0.f;
    for (int ki = 0; ki < 3; ++ki) {
        int hh = h - 1 + ki;
        if (hh < 0 || hh >= H_) continue;
        for (int kj = 0; kj < 3; ++kj) {
            int ww = w - 1 + kj;
            if (ww < 0 || ww >= W_) continue;
            int p = hh * W_ + ww;
            int kk = ki * 3 + kj;
            acc += ca_w1[kk] * avg[p] + ca_w1[9 + kk] * mxp[p] + ca_w2[kk] * var[p];
        }
    }
    yb[idx] = sigm(acc);
}

// ---------------- xd = w_down @ x ----------------
__global__ void k_xd(const float* __restrict__ x, const float* __restrict__ w_down,
                     float* __restrict__ xd) {
    int idx = blockIdx.x * 256 + threadIdx.x;
    if (idx >= RC_ * THW_) return;
    int r = idx / THW_, thw = idx % THW_;
    float acc = 0.f;
    #pragma unroll 8
    for (int c = 0; c < C_; ++c) acc += w_down[r * C_ + c] * x[c * THW_ + thw];
    xd[idx] = acc;
}

// ---------------- agg0 = sum_i weights[i] * dwconv3d_i(xd) ----------------
__global__ void k_agg(const float* __restrict__ xd,
                      const float* __restrict__ w1, const float* __restrict__ b1,
                      const float* __restrict__ w2, const float* __restrict__ b2,
                      const float* __restrict__ w3, const float* __restrict__ b3,
                      const float* __restrict__ wts, float* __restrict__ agg0) {
    int idx = blockIdx.x * 256 + threadIdx.x;
    if (idx >= RC_ * THW_) return;
    int w = idx % W_;
    int h = (idx / W_) % H_;
    int t = (idx / HW_) % T_;
    int r = idx / THW_;
    const float* xr = xd + r * THW_;
    const float* wk_arr[3] = {w1, w2, w3};
    const float* bs_arr[3] = {b1, b2, b3};
    float tot = 0.f;
    for (int m = 0; m < 3; ++m) {
        int dil = m + 1;
        float acc = bs_arr[m][r];
        const float* wk = wk_arr[m] + r * 81;
        for (int kt = 0; kt < 9; ++kt) {
            int tt = t - 4 + kt;
            if (tt < 0 || tt >= T_) continue;
            for (int kh = 0; kh < 3; ++kh) {
                int hh = h + (kh - 1) * dil;
                if (hh < 0 || hh >= H_) continue;
                for (int kw = 0; kw < 3; ++kw) {
                    int wwp = w + (kw - 1) * dil;
                    if (wwp < 0 || wwp >= W_) continue;
                    acc += xr[tt * HW_ + hh * W_ + wwp] * wk[kt * 9 + kh * 3 + kw];
                }
            }
        }
        tot += acc * wts[m];
    }
    agg0[idx] = tot;
}

// ---------------- k_final (round-7 verbatim): per-side aff->sigmoid->PV ----------
__global__ __launch_bounds__(256) void k_final(const float* __restrict__ x,
                                               const float* __restrict__ part,
                                               const float* __restrict__ yb,
                                               const float* __restrict__ weights2,
                                               float* __restrict__ featP) {
    int bid = blockIdx.x;
    int side = bid / (T_ * 36);
    int rem = bid % (T_ * 36);
    int t = rem / 36, hwt = rem % 36;
    int base = t * HW_ + hwt * 64;
    __shared__ float xs[64 * LP_];
    __shared__ float ps[64 * LP_];
    __shared__ float wt[64 * LP_];
    int tid = threadIdx.x;
    for (int i = tid; i < 4096; i += 256)
        xs[(i >> 6) * LP_ + (i & 63)] = x[(i >> 6) * THW_ + base + (i & 63)];
    int hw_grpA = tid >> 4, sd_grp = tid & 15;
    int hwB = tid & 63, wv = tid >> 6;
    const float4* xs4 = (const float4*)xs;
    const float4* ps4 = (const float4*)ps;
    const float4* wt4c = (const float4*)wt;
    float4* wt4 = (float4*)wt;
    const float* pslab = part + (size_t)(side * T_ + t) * C_ * SD_;
    float yv[4];
    #pragma unroll
    for (int g = 0; g < 4; ++g) yv[g] = yb[side * THW_ + base + hw_grpA * 4 + g];
    float accB[16] = {};
    for (int kt = 0; kt < 9; ++kt) {
        __syncthreads();
        for (int i = tid; i < 4096; i += 256)
            ps[(i >> 6) * LP_ + (i & 63)] = pslab[(i >> 6) * SD_ + kt * 64 + (i & 63)];
        __syncthreads();
        {
            float acc[4][4] = {};
            for (int c = 0; c < 64; ++c) {
                float xa[4], pa[4];
                *(float4*)xa = xs4[c * LP4_ + hw_grpA];
                *(float4*)pa = ps4[c * LP4_ + sd_grp];
                #pragma unroll
                for (int g = 0; g < 4; ++g)
                    #pragma unroll
                    for (int j = 0; j < 4; ++j) acc[g][j] += xa[g] * pa[j];
            }
            #pragma unroll
            for (int g = 0; g < 4; ++g) {
                float w4[4];
                #pragma unroll
                for (int j = 0; j < 4; ++j) w4[j] = sigm(acc[g][j] * yv[g]) - 0.5f;
                wt4[(hw_grpA * 4 + g) * LP4_ + sd_grp] = *(float4*)w4;
            }
        }
        __syncthreads();
        for (int sd4 = 0; sd4 < 16; ++sd4) {
            float wa[4];
            *(float4*)wa = wt4c[hwB * LP4_ + sd4];
            #pragma unroll
            for (int k = 0; k < 16; ++k) {
                float pa[4];
                *(float4*)pa = ps4[(wv * 16 + k) * LP4_ + sd4];
                #pragma unroll
                for (int jj = 0; jj < 4; ++jj) accB[k] += pa[jj] * wa[jj];
            }
        }
    }
    float w2s = weights2[side];
    #pragma unroll
    for (int k = 0; k < 16; ++k)
        featP[(size_t)side * CTHW_ + (wv * 16 + k) * THW_ + base + hwB] = accB[k] * w2s;
}

// ---------------- k_out: out = (featP0+featP1) * (sigm(w_back@agg0)-0.5) ----------
__global__ void k_out(const float* __restrict__ featP, const float* __restrict__ agg0,
                      const float* __restrict__ w_back, float* __restrict__ out) {
    int idx = blockIdx.x * 256 + threadIdx.x;
    if (idx >= CTHW_) return;
    int o = idx / THW_, thw = idx % THW_;
    float a = 0.f;
    #pragma unroll
    for (int r = 0; r < RC_; ++r) a += w_back[o * RC_ + r] * agg0[r * THW_ + thw];
    out[idx] = (featP[idx] + featP[CTHW_ + idx]) * (sigm(a) - 0.5f);
}

extern "C" void kernel_launch(void* const* d_in, const int* in_sizes, int n_in,
                              void* d_out, int out_size, void* d_ws, size_t ws_size,
                              hipStream_t stream) {
    const float* x       = (const float*)d_in[0];
    const float* w_dc2   = (const float*)d_in[1];
    const float* w_ofs_l = (const float*)d_in[2];
    const float* b_ofs_l = (const float*)d_in[3];
    const float* w_ofs_r = (const float*)d_in[4];
    const float* b_ofs_r = (const float*)d_in[5];
    const float* ca_w1   = (const float*)d_in[6];
    const float* ca_w2   = (const float*)d_in[7];
    const float* w_down  = (const float*)d_in[8];
    const float* sa1_w   = (const float*)d_in[9];
    const float* sa1_b   = (const float*)d_in[10];
    const float* sa2_w   = (const float*)d_in[11];
    const float* sa2_b   = (const float*)d_in[12];
    const float* sa3_w   = (const float*)d_in[13];
    const float* sa3_b   = (const float*)d_in[14];
    const float* weights = (const float*)d_in[15];
    const float* weights2= (const float*)d_in[16];
    const float* w_back  = (const float*)d_in[17];
    float* out = (float*)d_out;

    // f32 workspace 26.1 MB (== round-7 proven size), with overlays:
    //   featP[0:CTHW)  == x2T   (x2T dead after k_gs; featP0 written by k_final later)
    //   featP[CTHW:2C) == partC (partC dead after k_tr; featP1 written by k_final later)
    float* ws    = (float*)d_ws;
    float* featP = ws;                 // [2][CTHW_]
    float* x2T   = ws;                 // alias featP side 0
    float* partC = ws + CTHW_;         // alias featP side 1 (needs 1,179,648 < CTHW_)
    float* part  = ws + 2 * CTHW_;     // 1,179,648  [st][c][sd]
    float* off   = part + 2 * T_ * C_ * SD_;   // 36,864
    float* stats = off + 2 * T_ * 2 * SD_;     // 221,184
    float* yb    = stats + 2 * 3 * THW_;       // 73,728
    float* xd    = yb + 2 * THW_;              // 147,456
    float* agg0  = xd + RC_ * THW_;            // 147,456

    k_x2<<<THW_ / 64, 256, 0, stream>>>(x, w_dc2, x2T);
    k_off<<<(2 * 16 * 576) / 4, 256, 0, stream>>>(x, x2T, w_ofs_l, b_ofs_l,
                                                  w_ofs_r, b_ofs_r, off);
    k_gs<<<(2 * 16 * 576) / 4, 256, 0, stream>>>(x2T, off, partC);
    k_tr<<<32 * 9, 256, 0, stream>>>(partC, part);
    k_stats<<<2 * T_ * 36, 256, 0, stream>>>(x, part, stats);
    k_attn<<<(2 * THW_) / 256, 256, 0, stream>>>(stats, ca_w1, ca_w2, yb);
    k_xd<<<(RC_ * THW_) / 256, 256, 0, stream>>>(x, w_down, xd);
    k_agg<<<(RC_ * THW_) / 256, 256, 0, stream>>>(xd, sa1_w, sa1_b, sa2_w, sa2_b,
                                                  sa3_w, sa3_b, weights, agg0);
    k_final<<<2 * T_ * 36, 256, 0, stream>>>(x, part, yb, weights2, featP);
    k_out<<<CTHW_ / 256, 256, 0, stream>>>(featP, agg0, w_back, out);
}

// Round 10
// 337.288 us; speedup vs baseline: 11.6700x; 1.5219x over previous
//
#include <hip/hip_runtime.h>
#include <hip/hip_bf16.h>

#define T_    16
#define C_    64
#define H_    48
#define W_    48
#define HW_   2304
#define THW_  36864
#define CTHW_ 2359296
#define H2_   24
#define W2_   24
#define SD_   576
#define RC_   4
#define SDT_  72    // bf16 LDS tile row stride in shorts (144 B, 16B-multiple)

typedef short short8 __attribute__((ext_vector_type(8)));
typedef float f32x4 __attribute__((ext_vector_type(4)));

__device__ __forceinline__ float sigm(float v) { return 1.f / (1.f + __expf(-v)); }
__device__ __forceinline__ unsigned short f2bf(float v) {
    __hip_bfloat16 h = __float2bfloat16(v);
    union { __hip_bfloat16 h; unsigned short u; } cv; cv.h = h; return cv.u;
}
__device__ __forceinline__ float bf2f(unsigned short u) {
    return __uint_as_float((unsigned)u << 16);
}

// ---------------- k_x2 (round-9 verbatim): x2T[thw][o] = w_dc2 @ x ----------------
__global__ __launch_bounds__(256) void k_x2(const float* __restrict__ x,
                                            const float* __restrict__ w,
                                            float* __restrict__ x2T) {
    int base = blockIdx.x * 64;
    __shared__ float wl[64 * 65];
    __shared__ float xt[4096];
    int tid = threadIdx.x;
    for (int i = tid; i < 4096; i += 256) wl[(i >> 6) * 65 + (i & 63)] = w[i];
    for (int i = tid; i < 4096; i += 256) xt[i] = x[(i >> 6) * THW_ + base + (i & 63)];
    __syncthreads();
    int o_grp = tid >> 4, u_grp = tid & 15;
    float acc[4][4] = {};
    const float4* xt4 = (const float4*)xt;
    for (int c = 0; c < 64; ++c) {
        float xa[4];
        *(float4*)xa = xt4[c * 16 + u_grp];
        #pragma unroll
        for (int i = 0; i < 4; ++i) {
            float wv = wl[(o_grp * 4 + i) * 65 + c];
            #pragma unroll
            for (int g = 0; g < 4; ++g) acc[i][g] += wv * xa[g];
        }
    }
    #pragma unroll
    for (int g = 0; g < 4; ++g) {
        float4 v = make_float4(acc[0][g], acc[1][g], acc[2][g], acc[3][g]);
        *(float4*)&x2T[(size_t)(base + u_grp * 4 + g) * 64 + o_grp * 4] = v;
    }
}

// ---------------- k_xb: xbh/xbl bf16 split of x, channel-last [thw][c] ----------------
__global__ __launch_bounds__(256) void k_xb(const float* __restrict__ x,
                                            unsigned short* __restrict__ xbh,
                                            unsigned short* __restrict__ xbl) {
    int base = blockIdx.x * 64;
    __shared__ float ld[64 * 65];
    int tid = threadIdx.x;
    for (int i = tid; i < 4096; i += 256) {
        int c = i >> 6, u = i & 63;
        ld[c * 65 + u] = x[(size_t)c * THW_ + base + u];
    }
    __syncthreads();
    for (int i = tid; i < 4096; i += 256) {
        int u = i >> 6, c = i & 63;
        float v = ld[c * 65 + u];
        unsigned short h = f2bf(v);
        xbh[(size_t)(base + u) * 64 + c] = h;
        xbl[(size_t)(base + u) * 64 + c] = f2bf(v - bf2f(h));
    }
}

// ---------------- k_off (round-9 verbatim) ----------------
__global__ __launch_bounds__(256) void k_off(const float* __restrict__ x,
                                             const float* __restrict__ x2T,
                                             const float* __restrict__ w_l,
                                             const float* __restrict__ b_l,
                                             const float* __restrict__ w_r,
                                             const float* __restrict__ b_r,
                                             float* __restrict__ off) {
    __shared__ float wlds[2304];
    int tid = threadIdx.x;
    for (int i = tid; i < 2304; i += 256) wlds[i] = (i < 1152) ? w_l[i] : w_r[i - 1152];
    __syncthreads();
    int wg = blockIdx.x * 4 + (tid >> 6);
    int lane = tid & 63;
    int j = wg % 24, i = (wg / 24) % 24, t = (wg / 576) % 16, side = wg / 9216;
    int ts = (side == 0) ? min(t + 1, T_ - 1) : max(t - 1, 0);
    const float* wp = wlds + side * 1152;
    const float* xl = x + (size_t)lane * THW_ + t * HW_;
    const float* x2l = x2T + (size_t)ts * HW_ * 64 + lane;
    float a0 = 0.f, a1 = 0.f;
    for (int ki = 0; ki < 3; ++ki) {
        int hh = 2 * i - 1 + ki;
        if (hh < 0 || hh >= H_) continue;
        for (int kj = 0; kj < 3; ++kj) {
            int ww = 2 * j - 1 + kj;
            if (ww < 0 || ww >= W_) continue;
            int pos = hh * W_ + ww;
            float s = xl[pos] + x2l[(size_t)pos * 64];
            int tap = ki * 3 + kj;
            a0 += s * wp[lane * 9 + tap];
            a1 += s * wp[576 + lane * 9 + tap];
        }
    }
    #pragma unroll
    for (int m = 32; m >= 1; m >>= 1) {
        a0 += __shfl_xor(a0, m);
        a1 += __shfl_xor(a1, m);
    }
    if (lane == 0) {
        const float* bb = (side == 0) ? b_l : b_r;
        int ob = (side * 16 + t) * 1152 + i * 24 + j;
        off[ob] = a0 + bb[0];
        off[ob + 576] = a1 + bb[1];
    }
}

// ---------------- k_gs: grid sample -> partCb hi/lo bf16 [st][sd][c] ----------------
__global__ __launch_bounds__(256) void k_gs(const float* __restrict__ x2T,
                                            const float* __restrict__ off,
                                            unsigned short* __restrict__ pch,
                                            unsigned short* __restrict__ pcl) {
    int wg = blockIdx.x * 4 + (threadIdx.x >> 6);
    int lane = threadIdx.x & 63;
    int sd = wg % 576;
    int t = (wg / 576) % 16;
    int side = wg / 9216;
    int d = sd % W2_, s = sd / W2_;
    const float* offp = off + (side * 16 + t) * 1152;
    float v0 = 2.f * (float)d + offp[sd];
    float v1 = 2.f * (float)s + offp[576 + sd];
    float xf = 48.f * v0 / 23.f - 0.5f;
    float yf = 48.f * v1 / 23.f - 0.5f;
    float x0 = floorf(xf), y0 = floorf(yf);
    int ix0 = (int)x0, iy0 = (int)y0;
    float fx = xf - x0, fy = yf - y0;
    float w00 = (1.f - fx) * (1.f - fy), w10 = fx * (1.f - fy);
    float w01 = (1.f - fx) * fy,         w11 = fx * fy;
    bool vx0 = (ix0 >= 0 && ix0 < W_), vx1 = (ix0 + 1 >= 0 && ix0 + 1 < W_);
    bool vy0 = (iy0 >= 0 && iy0 < H_), vy1 = (iy0 + 1 >= 0 && iy0 + 1 < H_);
    int cx0 = min(max(ix0, 0), W_ - 1), cx1 = min(max(ix0 + 1, 0), W_ - 1);
    int cy0 = min(max(iy0, 0), H_ - 1), cy1 = min(max(iy0 + 1, 0), H_ - 1);
    float m00 = (vx0 && vy0) ? w00 : 0.f;
    float m10 = (vx1 && vy0) ? w10 : 0.f;
    float m01 = (vx0 && vy1) ? w01 : 0.f;
    float m11 = (vx1 && vy1) ? w11 : 0.f;
    int ts = (side == 0) ? min(t + 1, T_ - 1) : max(t - 1, 0);
    const float* img = x2T + (size_t)ts * HW_ * 64;
    float val = m00 * img[(size_t)(cy0 * W_ + cx0) * 64 + lane]
              + m10 * img[(size_t)(cy0 * W_ + cx1) * 64 + lane]
              + m01 * img[(size_t)(cy1 * W_ + cx0) * 64 + lane]
              + m11 * img[(size_t)(cy1 * W_ + cx1) * 64 + lane];
    size_t idx = ((size_t)(side * 16 + t) * 576 + sd) * 64 + lane;
    unsigned short h = f2bf(val);
    pch[idx] = h;
    pcl[idx] = f2bf(val - bf2f(h));
}

// ---------------- k_tr: transpose pch [st][sd][c] -> partb [st][c][sd] (bf16) ----------
__global__ __launch_bounds__(256) void k_tr(const unsigned short* __restrict__ pch,
                                            unsigned short* __restrict__ partb) {
    int st = blockIdx.x / 9;
    int sdt = blockIdx.x % 9;
    __shared__ unsigned short ld[64 * 68];
    int tid = threadIdx.x;
    const unsigned short* src = pch + ((size_t)st * 576 + sdt * 64) * 64;
    for (int i = tid; i < 4096; i += 256) ld[(i >> 6) * 68 + (i & 63)] = src[i];
    __syncthreads();
    unsigned short* dst = partb + (size_t)st * 64 * 576 + sdt * 64;
    for (int i = tid; i < 4096; i += 256) {
        int c = i >> 6, sdl = i & 63;
        dst[(size_t)c * 576 + sdl] = ld[sdl * 68 + c];
    }
}

// ---------------- k_stats: MFMA split-bf16 aff GEMM + stats over sd ----------------
// grid: side(2) x t(16) x hw-tile(36)
__global__ __launch_bounds__(256) void k_stats(const unsigned short* __restrict__ xbh,
                                               const unsigned short* __restrict__ xbl,
                                               const unsigned short* __restrict__ pch,
                                               const unsigned short* __restrict__ pcl,
                                               float* __restrict__ stats) {
    int bid = blockIdx.x;
    int side = bid / (16 * 36);
    int rem = bid % (16 * 36);
    int t = rem / 36, hwt = rem % 36;
    int base = t * HW_ + hwt * 64;
    __shared__ __attribute__((aligned(16))) unsigned short xsh[64 * SDT_];
    __shared__ __attribute__((aligned(16))) unsigned short xsl[64 * SDT_];
    __shared__ __attribute__((aligned(16))) unsigned short pah[64 * SDT_];
    __shared__ __attribute__((aligned(16))) unsigned short pal[64 * SDT_];
    int tid = threadIdx.x;
    int lane = tid & 63, wv = tid >> 6;
    int quad = lane >> 4, l15 = lane & 15;
    int m0 = wv * 16;
    for (int i = tid; i < 1024; i += 256) {
        int hw = i >> 4, c4 = i & 15;
        *(uint2*)&xsh[hw * SDT_ + c4 * 4] = *(const uint2*)&xbh[(size_t)(base + hw) * 64 + c4 * 4];
        *(uint2*)&xsl[hw * SDT_ + c4 * 4] = *(const uint2*)&xbl[(size_t)(base + hw) * 64 + c4 * 4];
    }
    const unsigned short* ph = pch + (size_t)(side * 16 + t) * 576 * 64;
    const unsigned short* pl = pcl + (size_t)(side * 16 + t) * 576 * 64;
    float sum[4] = {0,0,0,0}, sq[4] = {0,0,0,0}, mx[4] = {-1e30f,-1e30f,-1e30f,-1e30f};
    for (int kt = 0; kt < 9; ++kt) {
        __syncthreads();
        for (int i = tid; i < 1024; i += 256) {
            int sd = i >> 4, c4 = i & 15;
            *(uint2*)&pah[sd * SDT_ + c4 * 4] = *(const uint2*)&ph[(size_t)(kt * 64 + sd) * 64 + c4 * 4];
            *(uint2*)&pal[sd * SDT_ + c4 * 4] = *(const uint2*)&pl[(size_t)(kt * 64 + sd) * 64 + c4 * 4];
        }
        __syncthreads();
        short8 ah0 = *(const short8*)&xsh[(m0 + l15) * SDT_ + quad * 8];
        short8 ah1 = *(const short8*)&xsh[(m0 + l15) * SDT_ + 32 + quad * 8];
        short8 al0 = *(const short8*)&xsl[(m0 + l15) * SDT_ + quad * 8];
        short8 al1 = *(const short8*)&xsl[(m0 + l15) * SDT_ + 32 + quad * 8];
        #pragma unroll
        for (int tile = 0; tile < 4; ++tile) {
            short8 bh0 = *(const short8*)&pah[(tile * 16 + l15) * SDT_ + quad * 8];
            short8 bh1 = *(const short8*)&pah[(tile * 16 + l15) * SDT_ + 32 + quad * 8];
            short8 bl0 = *(const short8*)&pal[(tile * 16 + l15) * SDT_ + quad * 8];
            short8 bl1 = *(const short8*)&pal[(tile * 16 + l15) * SDT_ + 32 + quad * 8];
            f32x4 dacc = {0.f, 0.f, 0.f, 0.f};
            dacc = __builtin_amdgcn_mfma_f32_16x16x32_bf16(ah0, bh0, dacc, 0, 0, 0);
            dacc = __builtin_amdgcn_mfma_f32_16x16x32_bf16(ah1, bh1, dacc, 0, 0, 0);
            dacc = __builtin_amdgcn_mfma_f32_16x16x32_bf16(ah0, bl0, dacc, 0, 0, 0);
            dacc = __builtin_amdgcn_mfma_f32_16x16x32_bf16(ah1, bl1, dacc, 0, 0, 0);
            dacc = __builtin_amdgcn_mfma_f32_16x16x32_bf16(al0, bh0, dacc, 0, 0, 0);
            dacc = __builtin_amdgcn_mfma_f32_16x16x32_bf16(al1, bh1, dacc, 0, 0, 0);
            #pragma unroll
            for (int r = 0; r < 4; ++r) {
                float v = dacc[r];
                sum[r] += v; sq[r] += v * v; mx[r] = fmaxf(mx[r], v);
            }
        }
    }
    #pragma unroll
    for (int m = 1; m < 16; m <<= 1)
        #pragma unroll
        for (int r = 0; r < 4; ++r) {
            sum[r] += __shfl_xor(sum[r], m);
            sq[r]  += __shfl_xor(sq[r], m);
            mx[r]   = fmaxf(mx[r], __shfl_xor(mx[r], m));
        }
    if (l15 == 0) {
        #pragma unroll
        for (int r = 0; r < 4; ++r) {
            int thw = base + m0 + quad * 4 + r;
            stats[(side * 3 + 0) * THW_ + thw] = sum[r] * (1.f / 576.f);
            stats[(side * 3 + 1) * THW_ + thw] = mx[r];
            stats[(side * 3 + 2) * THW_ + thw] = (sq[r] - sum[r] * sum[r] * (1.f / 576.f)) * (1.f / 575.f);
        }
    }
}

// ---------------- k_attn (verbatim) ----------------
__global__ void k_attn(const float* __restrict__ stats, const float* __restrict__ ca_w1,
                       const float* __restrict__ ca_w2, float* __restrict__ yb) {
    int idx = blockIdx.x * 256 + threadIdx.x;
    if (idx >= 2 * THW_) return;
    int side = idx / THW_, thw = idx % THW_;
    int w = thw % W_, h = (thw / W_) % H_, t = thw / HW_;
    const float* avg = stats + (side * 3 + 0) * THW_ + t * HW_;
    const float* mxp = stats + (side * 3 + 1) * THW_ + t * HW_;
    const float* var = stats + (side * 3 + 2) * THW_ + t * HW_;
    float acc = 0.f;
    for (int ki = 0; ki < 3; ++ki) {
        int hh = h - 1 + ki;
        if (hh < 0 || hh >= H_) continue;
        for (int kj = 0; kj < 3; ++kj) {
            int ww = w - 1 + kj;
            if (ww < 0 || ww >= W_) continue;
            int p = hh * W_ + ww;
            int kk = ki * 3 + kj;
            acc += ca_w1[kk] * avg[p] + ca_w1[9 + kk] * mxp[p] + ca_w2[kk] * var[p];
        }
    }
    yb[idx] = sigm(acc);
}

// ---------------- xd = w_down @ x (verbatim) ----------------
__global__ void k_xd(const float* __restrict__ x, const float* __restrict__ w_down,
                     float* __restrict__ xd) {
    int idx = blockIdx.x * 256 + threadIdx.x;
    if (idx >= RC_ * THW_) return;
    int r = idx / THW_, thw = idx % THW_;
    float acc = 0.f;
    #pragma unroll 8
    for (int c = 0; c < C_; ++c) acc += w_down[r * C_ + c] * x[c * THW_ + thw];
    xd[idx] = acc;
}

// ---------------- k_agg (verbatim) ----------------
__global__ void k_agg(const float* __restrict__ xd,
                      const float* __restrict__ w1, const float* __restrict__ b1,
                      const float* __restrict__ w2, const float* __restrict__ b2,
                      const float* __restrict__ w3, const float* __restrict__ b3,
                      const float* __restrict__ wts, float* __restrict__ agg0) {
    int idx = blockIdx.x * 256 + threadIdx.x;
    if (idx >= RC_ * THW_) return;
    int w = idx % W_;
    int h = (idx / W_) % H_;
    int t = (idx / HW_) % T_;
    int r = idx / THW_;
    const float* xr = xd + r * THW_;
    const float* wk_arr[3] = {w1, w2, w3};
    const float* bs_arr[3] = {b1, b2, b3};
    float tot = 0.f;
    for (int m = 0; m < 3; ++m) {
        int dil = m + 1;
        float acc = bs_arr[m][r];
        const float* wk = wk_arr[m] + r * 81;
        for (int kt = 0; kt < 9; ++kt) {
            int tt = t - 4 + kt;
            if (tt < 0 || tt >= T_) continue;
            for (int kh = 0; kh < 3; ++kh) {
                int hh = h + (kh - 1) * dil;
                if (hh < 0 || hh >= H_) continue;
                for (int kw = 0; kw < 3; ++kw) {
                    int wwp = w + (kw - 1) * dil;
                    if (wwp < 0 || wwp >= W_) continue;
                    acc += xr[tt * HW_ + hh * W_ + wwp] * wk[kt * 9 + kh * 3 + kw];
                }
            }
        }
        tot += acc * wts[m];
    }
    agg0[idx] = tot;
}

// ---------------- k_final: MFMA split aff -> sigmoid weight -> MFMA PV; fused gate ------
// grid: t(16) x hw-tile(36); per-side dispatch. side0: out = acc*w2; side1: out = (out+acc*w2)*gate
__global__ __launch_bounds__(256) void k_final(const unsigned short* __restrict__ xbh,
                                               const unsigned short* __restrict__ xbl,
                                               const unsigned short* __restrict__ pch,
                                               const unsigned short* __restrict__ pcl,
                                               const unsigned short* __restrict__ partb,
                                               const float* __restrict__ yb,
                                               const float* __restrict__ weights2,
                                               const float* __restrict__ agg0,
                                               const float* __restrict__ w_back,
                                               int side, float* __restrict__ out) {
    int bid = blockIdx.x;
    int t = bid / 36, hwt = bid % 36;
    int base = t * HW_ + hwt * 64;
    __shared__ __attribute__((aligned(16))) unsigned short xsh[64 * SDT_];
    __shared__ __attribute__((aligned(16))) unsigned short xsl[64 * SDT_];
    __shared__ __attribute__((aligned(16))) unsigned short pah[64 * SDT_];
    __shared__ __attribute__((aligned(16))) unsigned short psL[64 * SDT_];  // psA_lo, then psB
    __shared__ __attribute__((aligned(16))) unsigned short wt[64 * SDT_];
    int tid = threadIdx.x;
    int lane = tid & 63, wv = tid >> 6;
    int quad = lane >> 4, l15 = lane & 15;
    int m0 = wv * 16;
    for (int i = tid; i < 1024; i += 256) {
        int hw = i >> 4, c4 = i & 15;
        *(uint2*)&xsh[hw * SDT_ + c4 * 4] = *(const uint2*)&xbh[(size_t)(base + hw) * 64 + c4 * 4];
        *(uint2*)&xsl[hw * SDT_ + c4 * 4] = *(const uint2*)&xbl[(size_t)(base + hw) * 64 + c4 * 4];
    }
    const unsigned short* ph = pch + (size_t)(side * 16 + t) * 576 * 64;
    const unsigned short* pl = pcl + (size_t)(side * 16 + t) * 576 * 64;
    const unsigned short* pb = partb + (size_t)(side * 16 + t) * 64 * 576;
    float yv[4];
    #pragma unroll
    for (int r = 0; r < 4; ++r) yv[r] = yb[side * THW_ + base + m0 + quad * 4 + r];
    f32x4 accB[4] = {{0.f,0.f,0.f,0.f},{0.f,0.f,0.f,0.f},{0.f,0.f,0.f,0.f},{0.f,0.f,0.f,0.f}};
    for (int kt = 0; kt < 9; ++kt) {
        __syncthreads();
        for (int i = tid; i < 1024; i += 256) {
            int sd = i >> 4, c4 = i & 15;
            *(uint2*)&pah[sd * SDT_ + c4 * 4] = *(const uint2*)&ph[(size_t)(kt * 64 + sd) * 64 + c4 * 4];
            *(uint2*)&psL[sd * SDT_ + c4 * 4] = *(const uint2*)&pl[(size_t)(kt * 64 + sd) * 64 + c4 * 4];
        }
        __syncthreads();
        // phase A: aff tile (split bf16) -> sigmoid weight -> wt[hw][sd]
        {
            short8 ah0 = *(const short8*)&xsh[(m0 + l15) * SDT_ + quad * 8];
            short8 ah1 = *(const short8*)&xsh[(m0 + l15) * SDT_ + 32 + quad * 8];
            short8 al0 = *(const short8*)&xsl[(m0 + l15) * SDT_ + quad * 8];
            short8 al1 = *(const short8*)&xsl[(m0 + l15) * SDT_ + 32 + quad * 8];
            #pragma unroll
            for (int tile = 0; tile < 4; ++tile) {
                short8 bh0 = *(const short8*)&pah[(tile * 16 + l15) * SDT_ + quad * 8];
                short8 bh1 = *(const short8*)&pah[(tile * 16 + l15) * SDT_ + 32 + quad * 8];
                short8 bl0 = *(const short8*)&psL[(tile * 16 + l15) * SDT_ + quad * 8];
                short8 bl1 = *(const short8*)&psL[(tile * 16 + l15) * SDT_ + 32 + quad * 8];
                f32x4 dacc = {0.f, 0.f, 0.f, 0.f};
                dacc = __builtin_amdgcn_mfma_f32_16x16x32_bf16(ah0, bh0, dacc, 0, 0, 0);
                dacc = __builtin_amdgcn_mfma_f32_16x16x32_bf16(ah1, bh1, dacc, 0, 0, 0);
                dacc = __builtin_amdgcn_mfma_f32_16x16x32_bf16(ah0, bl0, dacc, 0, 0, 0);
                dacc = __builtin_amdgcn_mfma_f32_16x16x32_bf16(ah1, bl1, dacc, 0, 0, 0);
                dacc = __builtin_amdgcn_mfma_f32_16x16x32_bf16(al0, bh0, dacc, 0, 0, 0);
                dacc = __builtin_amdgcn_mfma_f32_16x16x32_bf16(al1, bh1, dacc, 0, 0, 0);
                #pragma unroll
                for (int r = 0; r < 4; ++r)
                    wt[(m0 + quad * 4 + r) * SDT_ + tile * 16 + l15] =
                        f2bf(sigm(dacc[r] * yv[r]) - 0.5f);
            }
        }
        __syncthreads();
        // restage psL <- psB (part c-major, bf16)
        for (int i = tid; i < 1024; i += 256) {
            int c = i >> 4, s4 = i & 15;
            *(uint2*)&psL[c * SDT_ + s4 * 4] = *(const uint2*)&pb[(size_t)c * 576 + kt * 64 + s4 * 4];
        }
        __syncthreads();
        // phase B: accB[c-band][hw-tile] += P[c][sd] * wt[hw][sd]^T
        {
            short8 pA0 = *(const short8*)&psL[(m0 + l15) * SDT_ + quad * 8];
            short8 pA1 = *(const short8*)&psL[(m0 + l15) * SDT_ + 32 + quad * 8];
            #pragma unroll
            for (int tile = 0; tile < 4; ++tile) {
                short8 wb0 = *(const short8*)&wt[(tile * 16 + l15) * SDT_ + quad * 8];
                short8 wb1 = *(const short8*)&wt[(tile * 16 + l15) * SDT_ + 32 + quad * 8];
                accB[tile] = __builtin_amdgcn_mfma_f32_16x16x32_bf16(pA0, wb0, accB[tile], 0, 0, 0);
                accB[tile] = __builtin_amdgcn_mfma_f32_16x16x32_bf16(pA1, wb1, accB[tile], 0, 0, 0);
            }
        }
    }
    float w2s = weights2[side];
    #pragma unroll
    for (int tile = 0; tile < 4; ++tile) {
        int thw = base + tile * 16 + l15;
        #pragma unroll
        for (int r = 0; r < 4; ++r) {
            int c = m0 + quad * 4 + r;
            size_t oidx = (size_t)c * THW_ + thw;
            float v = accB[tile][r] * w2s;
            if (side == 0) {
                out[oidx] = v;
            } else {
                float a = 0.f;
                #pragma unroll
                for (int rr = 0; rr < RC_; ++rr) a += w_back[c * RC_ + rr] * agg0[rr * THW_ + thw];
                out[oidx] = (out[oidx] + v) * (sigm(a) - 0.5f);
            }
        }
    }
}

extern "C" void kernel_launch(void* const* d_in, const int* in_sizes, int n_in,
                              void* d_out, int out_size, void* d_ws, size_t ws_size,
                              hipStream_t stream) {
    const float* x       = (const float*)d_in[0];
    const float* w_dc2   = (const float*)d_in[1];
    const float* w_ofs_l = (const float*)d_in[2];
    const float* b_ofs_l = (const float*)d_in[3];
    const float* w_ofs_r = (const float*)d_in[4];
    const float* b_ofs_r = (const float*)d_in[5];
    const float* ca_w1   = (const float*)d_in[6];
    const float* ca_w2   = (const float*)d_in[7];
    const float* w_down  = (const float*)d_in[8];
    const float* sa1_w   = (const float*)d_in[9];
    const float* sa1_b   = (const float*)d_in[10];
    const float* sa2_w   = (const float*)d_in[11];
    const float* sa2_b   = (const float*)d_in[12];
    const float* sa3_w   = (const float*)d_in[13];
    const float* sa3_b   = (const float*)d_in[14];
    const float* weights = (const float*)d_in[15];
    const float* weights2= (const float*)d_in[16];
    const float* w_back  = (const float*)d_in[17];
    float* out = (float*)d_out;

    // workspace ~23.8 MB (< proven 26.1). x2T region (dead after k_gs) hosts
    // stats/yb/xd/agg0/partb overlays (all written only after k_gs completes).
    float* ws    = (float*)d_ws;
    float* x2T   = ws;                               // CTHW_ f32
    float* stats = x2T;                              // overlay: 221,184 f32
    float* yb    = stats + 2 * 3 * THW_;             // 73,728
    float* xd    = yb + 2 * THW_;                    // 147,456
    float* agg0  = xd + RC_ * THW_;                  // 147,456
    unsigned short* partb = (unsigned short*)(agg0 + RC_ * THW_);  // 1,179,648 u16 (fits in x2T region)
    float* off   = ws + CTHW_;                       // 36,864 f32
    unsigned short* xbh = (unsigned short*)(off + 2 * T_ * 2 * SD_);  // CTHW_ u16
    unsigned short* xbl = xbh + CTHW_;                                // CTHW_ u16
    unsigned short* pch = xbl + CTHW_;               // 1,179,648 u16
    unsigned short* pcl = pch + 2 * 16 * 576 * 64;   // 1,179,648 u16

    k_x2<<<THW_ / 64, 256, 0, stream>>>(x, w_dc2, x2T);
    k_xb<<<THW_ / 64, 256, 0, stream>>>(x, xbh, xbl);
    k_off<<<(2 * 16 * 576) / 4, 256, 0, stream>>>(x, x2T, w_ofs_l, b_ofs_l,
                                                  w_ofs_r, b_ofs_r, off);
    k_gs<<<(2 * 16 * 576) / 4, 256, 0, stream>>>(x2T, off, pch, pcl);
    k_tr<<<32 * 9, 256, 0, stream>>>(pch, partb);
    k_stats<<<2 * 16 * 36, 256, 0, stream>>>(xbh, xbl, pch, pcl, stats);
    k_attn<<<(2 * THW_) / 256, 256, 0, stream>>>(stats, ca_w1, ca_w2, yb);
    k_xd<<<(RC_ * THW_) / 256, 256, 0, stream>>>(x, w_down, xd);
    k_agg<<<(RC_ * THW_) / 256, 256, 0, stream>>>(xd, sa1_w, sa1_b, sa2_w, sa2_b,
                                                  sa3_w, sa3_b, weights, agg0);
    k_final<<<16 * 36, 256, 0, stream>>>(xbh, xbl, pch, pcl, partb, yb, weights2,
                                         agg0, w_back, 0, out);
    k_final<<<16 * 36, 256, 0, stream>>>(xbh, xbl, pch, pcl, partb, yb, weights2,
                                         agg0, w_back, 1, out);
}

// Round 11
// 317.570 us; speedup vs baseline: 12.3946x; 1.0621x over previous
//
#include <hip/hip_runtime.h>
#include <hip/hip_bf16.h>

#define T_    16
#define C_    64
#define H_    48
#define W_    48
#define HW_   2304
#define THW_  36864
#define CTHW_ 2359296
#define H2_   24
#define W2_   24
#define SD_   576
#define RC_   4
#define SDT_  72    // bf16 LDS tile row stride in shorts (144 B, 16B-multiple)

typedef short short8 __attribute__((ext_vector_type(8)));
typedef float f32x4 __attribute__((ext_vector_type(4)));

__device__ __forceinline__ float sigm(float v) { return 1.f / (1.f + __expf(-v)); }
__device__ __forceinline__ unsigned short f2bf(float v) {
    __hip_bfloat16 h = __float2bfloat16(v);
    union { __hip_bfloat16 h; unsigned short u; } cv; cv.h = h; return cv.u;
}
__device__ __forceinline__ float bf2f(unsigned short u) {
    return __uint_as_float((unsigned)u << 16);
}

// ---------------- k_pre: fused x2T GEMM + bf16 split of x + xd = w_down@x ----------------
__global__ __launch_bounds__(256) void k_pre(const float* __restrict__ x,
                                             const float* __restrict__ w,
                                             const float* __restrict__ w_down,
                                             float* __restrict__ x2T,
                                             unsigned short* __restrict__ xbh,
                                             unsigned short* __restrict__ xbl,
                                             float* __restrict__ xd) {
    int base = blockIdx.x * 64;
    __shared__ float wl[64 * 65];   // w_dc2 [o][c] padded
    __shared__ float xt[4096];      // [c][u] unpadded (row-major float4 reads)
    __shared__ float ld[64 * 65];   // [c][u] padded (column reads for transpose)
    __shared__ float wd[256];       // w_down [r][c]
    int tid = threadIdx.x;
    for (int i = tid; i < 4096; i += 256) wl[(i >> 6) * 65 + (i & 63)] = w[i];
    for (int i = tid; i < 4096; i += 256) {
        float v = x[(size_t)(i >> 6) * THW_ + base + (i & 63)];
        xt[i] = v;
        ld[(i >> 6) * 65 + (i & 63)] = v;
    }
    if (tid < 256) wd[tid] = w_down[tid];
    __syncthreads();
    // x2T GEMM (round-9/10 verbatim logic)
    {
        int o_grp = tid >> 4, u_grp = tid & 15;
        float acc[4][4] = {};
        const float4* xt4 = (const float4*)xt;
        for (int c = 0; c < 64; ++c) {
            float xa[4];
            *(float4*)xa = xt4[c * 16 + u_grp];
            #pragma unroll
            for (int i = 0; i < 4; ++i) {
                float wv = wl[(o_grp * 4 + i) * 65 + c];
                #pragma unroll
                for (int g = 0; g < 4; ++g) acc[i][g] += wv * xa[g];
            }
        }
        #pragma unroll
        for (int g = 0; g < 4; ++g) {
            float4 v = make_float4(acc[0][g], acc[1][g], acc[2][g], acc[3][g]);
            *(float4*)&x2T[(size_t)(base + u_grp * 4 + g) * 64 + o_grp * 4] = v;
        }
    }
    // xd: r = tid>>6, u = tid&63
    {
        int r = tid >> 6, u = tid & 63;
        float a = 0.f;
        #pragma unroll 8
        for (int c = 0; c < 64; ++c) a += wd[r * 64 + c] * xt[c * 64 + u];
        xd[(size_t)r * THW_ + base + u] = a;
    }
    // bf16 split, channel-last (k_xb verbatim logic)
    for (int i = tid; i < 4096; i += 256) {
        int u = i >> 6, c = i & 63;
        float v = ld[c * 65 + u];
        unsigned short h = f2bf(v);
        xbh[(size_t)(base + u) * 64 + c] = h;
        xbl[(size_t)(base + u) * 64 + c] = f2bf(v - bf2f(h));
    }
}

// ---------------- k_off (verbatim) ----------------
__global__ __launch_bounds__(256) void k_off(const float* __restrict__ x,
                                             const float* __restrict__ x2T,
                                             const float* __restrict__ w_l,
                                             const float* __restrict__ b_l,
                                             const float* __restrict__ w_r,
                                             const float* __restrict__ b_r,
                                             float* __restrict__ off) {
    __shared__ float wlds[2304];
    int tid = threadIdx.x;
    for (int i = tid; i < 2304; i += 256) wlds[i] = (i < 1152) ? w_l[i] : w_r[i - 1152];
    __syncthreads();
    int wg = blockIdx.x * 4 + (tid >> 6);
    int lane = tid & 63;
    int j = wg % 24, i = (wg / 24) % 24, t = (wg / 576) % 16, side = wg / 9216;
    int ts = (side == 0) ? min(t + 1, T_ - 1) : max(t - 1, 0);
    const float* wp = wlds + side * 1152;
    const float* xl = x + (size_t)lane * THW_ + t * HW_;
    const float* x2l = x2T + (size_t)ts * HW_ * 64 + lane;
    float a0 = 0.f, a1 = 0.f;
    for (int ki = 0; ki < 3; ++ki) {
        int hh = 2 * i - 1 + ki;
        if (hh < 0 || hh >= H_) continue;
        for (int kj = 0; kj < 3; ++kj) {
            int ww = 2 * j - 1 + kj;
            if (ww < 0 || ww >= W_) continue;
            int pos = hh * W_ + ww;
            float s = xl[pos] + x2l[(size_t)pos * 64];
            int tap = ki * 3 + kj;
            a0 += s * wp[lane * 9 + tap];
            a1 += s * wp[576 + lane * 9 + tap];
        }
    }
    #pragma unroll
    for (int m = 32; m >= 1; m >>= 1) {
        a0 += __shfl_xor(a0, m);
        a1 += __shfl_xor(a1, m);
    }
    if (lane == 0) {
        const float* bb = (side == 0) ? b_l : b_r;
        int ob = (side * 16 + t) * 1152 + i * 24 + j;
        off[ob] = a0 + bb[0];
        off[ob + 576] = a1 + bb[1];
    }
}

// ---------------- k_gs (verbatim) ----------------
__global__ __launch_bounds__(256) void k_gs(const float* __restrict__ x2T,
                                            const float* __restrict__ off,
                                            unsigned short* __restrict__ pch,
                                            unsigned short* __restrict__ pcl) {
    int wg = blockIdx.x * 4 + (threadIdx.x >> 6);
    int lane = threadIdx.x & 63;
    int sd = wg % 576;
    int t = (wg / 576) % 16;
    int side = wg / 9216;
    int d = sd % W2_, s = sd / W2_;
    const float* offp = off + (side * 16 + t) * 1152;
    float v0 = 2.f * (float)d + offp[sd];
    float v1 = 2.f * (float)s + offp[576 + sd];
    float xf = 48.f * v0 / 23.f - 0.5f;
    float yf = 48.f * v1 / 23.f - 0.5f;
    float x0 = floorf(xf), y0 = floorf(yf);
    int ix0 = (int)x0, iy0 = (int)y0;
    float fx = xf - x0, fy = yf - y0;
    float w00 = (1.f - fx) * (1.f - fy), w10 = fx * (1.f - fy);
    float w01 = (1.f - fx) * fy,         w11 = fx * fy;
    bool vx0 = (ix0 >= 0 && ix0 < W_), vx1 = (ix0 + 1 >= 0 && ix0 + 1 < W_);
    bool vy0 = (iy0 >= 0 && iy0 < H_), vy1 = (iy0 + 1 >= 0 && iy0 + 1 < H_);
    int cx0 = min(max(ix0, 0), W_ - 1), cx1 = min(max(ix0 + 1, 0), W_ - 1);
    int cy0 = min(max(iy0, 0), H_ - 1), cy1 = min(max(iy0 + 1, 0), H_ - 1);
    float m00 = (vx0 && vy0) ? w00 : 0.f;
    float m10 = (vx1 && vy0) ? w10 : 0.f;
    float m01 = (vx0 && vy1) ? w01 : 0.f;
    float m11 = (vx1 && vy1) ? w11 : 0.f;
    int ts = (side == 0) ? min(t + 1, T_ - 1) : max(t - 1, 0);
    const float* img = x2T + (size_t)ts * HW_ * 64;
    float val = m00 * img[(size_t)(cy0 * W_ + cx0) * 64 + lane]
              + m10 * img[(size_t)(cy0 * W_ + cx1) * 64 + lane]
              + m01 * img[(size_t)(cy1 * W_ + cx0) * 64 + lane]
              + m11 * img[(size_t)(cy1 * W_ + cx1) * 64 + lane];
    size_t idx = ((size_t)(side * 16 + t) * 576 + sd) * 64 + lane;
    unsigned short h = f2bf(val);
    pch[idx] = h;
    pcl[idx] = f2bf(val - bf2f(h));
}

// ---------------- k_tr (verbatim) ----------------
__global__ __launch_bounds__(256) void k_tr(const unsigned short* __restrict__ pch,
                                            unsigned short* __restrict__ partb) {
    int st = blockIdx.x / 9;
    int sdt = blockIdx.x % 9;
    __shared__ unsigned short ld[64 * 68];
    int tid = threadIdx.x;
    const unsigned short* src = pch + ((size_t)st * 576 + sdt * 64) * 64;
    for (int i = tid; i < 4096; i += 256) ld[(i >> 6) * 68 + (i & 63)] = src[i];
    __syncthreads();
    unsigned short* dst = partb + (size_t)st * 64 * 576 + sdt * 64;
    for (int i = tid; i < 4096; i += 256) {
        int c = i >> 6, sdl = i & 63;
        dst[(size_t)c * 576 + sdl] = ld[sdl * 68 + c];
    }
}

// ---------------- k_stats: MFMA split-bf16 aff GEMM + stats, BOTH sides per block -------
// grid: t(16) x hw-tile(36)
__global__ __launch_bounds__(256) void k_stats(const unsigned short* __restrict__ xbh,
                                               const unsigned short* __restrict__ xbl,
                                               const unsigned short* __restrict__ pch,
                                               const unsigned short* __restrict__ pcl,
                                               float* __restrict__ stats) {
    int bid = blockIdx.x;
    int t = bid / 36, hwt = bid % 36;
    int base = t * HW_ + hwt * 64;
    __shared__ __attribute__((aligned(16))) unsigned short xsh[64 * SDT_];
    __shared__ __attribute__((aligned(16))) unsigned short xsl[64 * SDT_];
    __shared__ __attribute__((aligned(16))) unsigned short pah[64 * SDT_];
    __shared__ __attribute__((aligned(16))) unsigned short pal[64 * SDT_];
    int tid = threadIdx.x;
    int lane = tid & 63, wv = tid >> 6;
    int quad = lane >> 4, l15 = lane & 15;
    int m0 = wv * 16;
    for (int i = tid; i < 1024; i += 256) {
        int hw = i >> 4, c4 = i & 15;
        *(uint2*)&xsh[hw * SDT_ + c4 * 4] = *(const uint2*)&xbh[(size_t)(base + hw) * 64 + c4 * 4];
        *(uint2*)&xsl[hw * SDT_ + c4 * 4] = *(const uint2*)&xbl[(size_t)(base + hw) * 64 + c4 * 4];
    }
    __syncthreads();
    short8 ah0 = *(const short8*)&xsh[(m0 + l15) * SDT_ + quad * 8];
    short8 ah1 = *(const short8*)&xsh[(m0 + l15) * SDT_ + 32 + quad * 8];
    short8 al0 = *(const short8*)&xsl[(m0 + l15) * SDT_ + quad * 8];
    short8 al1 = *(const short8*)&xsl[(m0 + l15) * SDT_ + 32 + quad * 8];
    for (int side = 0; side < 2; ++side) {
        const unsigned short* ph = pch + (size_t)(side * 16 + t) * 576 * 64;
        const unsigned short* pl = pcl + (size_t)(side * 16 + t) * 576 * 64;
        float sum[4] = {0,0,0,0}, sq[4] = {0,0,0,0}, mx[4] = {-1e30f,-1e30f,-1e30f,-1e30f};
        for (int kt = 0; kt < 9; ++kt) {
            __syncthreads();
            for (int i = tid; i < 1024; i += 256) {
                int sd = i >> 4, c4 = i & 15;
                *(uint2*)&pah[sd * SDT_ + c4 * 4] = *(const uint2*)&ph[(size_t)(kt * 64 + sd) * 64 + c4 * 4];
                *(uint2*)&pal[sd * SDT_ + c4 * 4] = *(const uint2*)&pl[(size_t)(kt * 64 + sd) * 64 + c4 * 4];
            }
            __syncthreads();
            #pragma unroll
            for (int tile = 0; tile < 4; ++tile) {
                short8 bh0 = *(const short8*)&pah[(tile * 16 + l15) * SDT_ + quad * 8];
                short8 bh1 = *(const short8*)&pah[(tile * 16 + l15) * SDT_ + 32 + quad * 8];
                short8 bl0 = *(const short8*)&pal[(tile * 16 + l15) * SDT_ + quad * 8];
                short8 bl1 = *(const short8*)&pal[(tile * 16 + l15) * SDT_ + 32 + quad * 8];
                f32x4 dacc = {0.f, 0.f, 0.f, 0.f};
                dacc = __builtin_amdgcn_mfma_f32_16x16x32_bf16(ah0, bh0, dacc, 0, 0, 0);
                dacc = __builtin_amdgcn_mfma_f32_16x16x32_bf16(ah1, bh1, dacc, 0, 0, 0);
                dacc = __builtin_amdgcn_mfma_f32_16x16x32_bf16(ah0, bl0, dacc, 0, 0, 0);
                dacc = __builtin_amdgcn_mfma_f32_16x16x32_bf16(ah1, bl1, dacc, 0, 0, 0);
                dacc = __builtin_amdgcn_mfma_f32_16x16x32_bf16(al0, bh0, dacc, 0, 0, 0);
                dacc = __builtin_amdgcn_mfma_f32_16x16x32_bf16(al1, bh1, dacc, 0, 0, 0);
                #pragma unroll
                for (int r = 0; r < 4; ++r) {
                    float v = dacc[r];
                    sum[r] += v; sq[r] += v * v; mx[r] = fmaxf(mx[r], v);
                }
            }
        }
        #pragma unroll
        for (int m = 1; m < 16; m <<= 1)
            #pragma unroll
            for (int r = 0; r < 4; ++r) {
                sum[r] += __shfl_xor(sum[r], m);
                sq[r]  += __shfl_xor(sq[r], m);
                mx[r]   = fmaxf(mx[r], __shfl_xor(mx[r], m));
            }
        if (l15 == 0) {
            #pragma unroll
            for (int r = 0; r < 4; ++r) {
                int thw = base + m0 + quad * 4 + r;
                stats[(side * 3 + 0) * THW_ + thw] = sum[r] * (1.f / 576.f);
                stats[(side * 3 + 1) * THW_ + thw] = mx[r];
                stats[(side * 3 + 2) * THW_ + thw] = (sq[r] - sum[r] * sum[r] * (1.f / 576.f)) * (1.f / 575.f);
            }
        }
    }
}

// ---------------- k_attn (verbatim) ----------------
__global__ void k_attn(const float* __restrict__ stats, const float* __restrict__ ca_w1,
                       const float* __restrict__ ca_w2, float* __restrict__ yb) {
    int idx = blockIdx.x * 256 + threadIdx.x;
    if (idx >= 2 * THW_) return;
    int side = idx / THW_, thw = idx % THW_;
    int w = thw % W_, h = (thw / W_) % H_, t = thw / HW_;
    const float* avg = stats + (side * 3 + 0) * THW_ + t * HW_;
    const float* mxp = stats + (side * 3 + 1) * THW_ + t * HW_;
    const float* var = stats + (side * 3 + 2) * THW_ + t * HW_;
    float acc = 0.f;
    for (int ki = 0; ki < 3; ++ki) {
        int hh = h - 1 + ki;
        if (hh < 0 || hh >= H_) continue;
        for (int kj = 0; kj < 3; ++kj) {
            int ww = w - 1 + kj;
            if (ww < 0 || ww >= W_) continue;
            int p = hh * W_ + ww;
            int kk = ki * 3 + kj;
            acc += ca_w1[kk] * avg[p] + ca_w1[9 + kk] * mxp[p] + ca_w2[kk] * var[p];
        }
    }
    yb[idx] = sigm(acc);
}

// ---------------- k_agg (verbatim) ----------------
__global__ void k_agg(const float* __restrict__ xd,
                      const float* __restrict__ w1, const float* __restrict__ b1,
                      const float* __restrict__ w2, const float* __restrict__ b2,
                      const float* __restrict__ w3, const float* __restrict__ b3,
                      const float* __restrict__ wts, float* __restrict__ agg0) {
    int idx = blockIdx.x * 256 + threadIdx.x;
    if (idx >= RC_ * THW_) return;
    int w = idx % W_;
    int h = (idx / W_) % H_;
    int t = (idx / HW_) % T_;
    int r = idx / THW_;
    const float* xr = xd + r * THW_;
    const float* wk_arr[3] = {w1, w2, w3};
    const float* bs_arr[3] = {b1, b2, b3};
    float tot = 0.f;
    for (int m = 0; m < 3; ++m) {
        int dil = m + 1;
        float acc = bs_arr[m][r];
        const float* wk = wk_arr[m] + r * 81;
        for (int kt = 0; kt < 9; ++kt) {
            int tt = t - 4 + kt;
            if (tt < 0 || tt >= T_) continue;
            for (int kh = 0; kh < 3; ++kh) {
                int hh = h + (kh - 1) * dil;
                if (hh < 0 || hh >= H_) continue;
                for (int kw = 0; kw < 3; ++kw) {
                    int wwp = w + (kw - 1) * dil;
                    if (wwp < 0 || wwp >= W_) continue;
                    acc += xr[tt * HW_ + hh * W_ + wwp] * wk[kt * 9 + kh * 3 + kw];
                }
            }
        }
        tot += acc * wts[m];
    }
    agg0[idx] = tot;
}

// ---------------- k_final: BOTH sides + fused gate, one dispatch ----------------
// grid: t(16) x hw-tile(36)
__global__ __launch_bounds__(256) void k_final(const unsigned short* __restrict__ xbh,
                                               const unsigned short* __restrict__ xbl,
                                               const unsigned short* __restrict__ pch,
                                               const unsigned short* __restrict__ pcl,
                                               const unsigned short* __restrict__ partb,
                                               const float* __restrict__ yb,
                                               const float* __restrict__ weights2,
                                               const float* __restrict__ agg0,
                                               const float* __restrict__ w_back,
                                               float* __restrict__ out) {
    int bid = blockIdx.x;
    int t = bid / 36, hwt = bid % 36;
    int base = t * HW_ + hwt * 64;
    __shared__ __attribute__((aligned(16))) unsigned short xsh[64 * SDT_];
    __shared__ __attribute__((aligned(16))) unsigned short xsl[64 * SDT_];
    __shared__ __attribute__((aligned(16))) unsigned short pah[64 * SDT_];
    __shared__ __attribute__((aligned(16))) unsigned short psL[64 * SDT_];  // pl, then pb
    __shared__ __attribute__((aligned(16))) unsigned short wt[64 * SDT_];
    int tid = threadIdx.x;
    int lane = tid & 63, wv = tid >> 6;
    int quad = lane >> 4, l15 = lane & 15;
    int m0 = wv * 16;
    for (int i = tid; i < 1024; i += 256) {
        int hw = i >> 4, c4 = i & 15;
        *(uint2*)&xsh[hw * SDT_ + c4 * 4] = *(const uint2*)&xbh[(size_t)(base + hw) * 64 + c4 * 4];
        *(uint2*)&xsl[hw * SDT_ + c4 * 4] = *(const uint2*)&xbl[(size_t)(base + hw) * 64 + c4 * 4];
    }
    __syncthreads();
    short8 ah0 = *(const short8*)&xsh[(m0 + l15) * SDT_ + quad * 8];
    short8 ah1 = *(const short8*)&xsh[(m0 + l15) * SDT_ + 32 + quad * 8];
    short8 al0 = *(const short8*)&xsl[(m0 + l15) * SDT_ + quad * 8];
    short8 al1 = *(const short8*)&xsl[(m0 + l15) * SDT_ + 32 + quad * 8];
    float yv2[2][4];
    #pragma unroll
    for (int s = 0; s < 2; ++s)
        #pragma unroll
        for (int r = 0; r < 4; ++r) yv2[s][r] = yb[s * THW_ + base + m0 + quad * 4 + r];
    f32x4 acc2[2][4] = {};
    for (int side = 0; side < 2; ++side) {
        const unsigned short* ph = pch + (size_t)(side * 16 + t) * 576 * 64;
        const unsigned short* pl = pcl + (size_t)(side * 16 + t) * 576 * 64;
        const unsigned short* pb = partb + (size_t)(side * 16 + t) * 64 * 576;
        for (int kt = 0; kt < 9; ++kt) {
            __syncthreads();
            for (int i = tid; i < 1024; i += 256) {
                int sd = i >> 4, c4 = i & 15;
                *(uint2*)&pah[sd * SDT_ + c4 * 4] = *(const uint2*)&ph[(size_t)(kt * 64 + sd) * 64 + c4 * 4];
                *(uint2*)&psL[sd * SDT_ + c4 * 4] = *(const uint2*)&pl[(size_t)(kt * 64 + sd) * 64 + c4 * 4];
            }
            __syncthreads();
            // phase A: aff tile (split bf16) -> sigmoid weight -> wt[hw][sd]
            #pragma unroll
            for (int tile = 0; tile < 4; ++tile) {
                short8 bh0 = *(const short8*)&pah[(tile * 16 + l15) * SDT_ + quad * 8];
                short8 bh1 = *(const short8*)&pah[(tile * 16 + l15) * SDT_ + 32 + quad * 8];
                short8 bl0 = *(const short8*)&psL[(tile * 16 + l15) * SDT_ + quad * 8];
                short8 bl1 = *(const short8*)&psL[(tile * 16 + l15) * SDT_ + 32 + quad * 8];
                f32x4 dacc = {0.f, 0.f, 0.f, 0.f};
                dacc = __builtin_amdgcn_mfma_f32_16x16x32_bf16(ah0, bh0, dacc, 0, 0, 0);
                dacc = __builtin_amdgcn_mfma_f32_16x16x32_bf16(ah1, bh1, dacc, 0, 0, 0);
                dacc = __builtin_amdgcn_mfma_f32_16x16x32_bf16(ah0, bl0, dacc, 0, 0, 0);
                dacc = __builtin_amdgcn_mfma_f32_16x16x32_bf16(ah1, bl1, dacc, 0, 0, 0);
                dacc = __builtin_amdgcn_mfma_f32_16x16x32_bf16(al0, bh0, dacc, 0, 0, 0);
                dacc = __builtin_amdgcn_mfma_f32_16x16x32_bf16(al1, bh1, dacc, 0, 0, 0);
                #pragma unroll
                for (int r = 0; r < 4; ++r)
                    wt[(m0 + quad * 4 + r) * SDT_ + tile * 16 + l15] =
                        f2bf(sigm(dacc[r] * yv2[side][r]) - 0.5f);
            }
            __syncthreads();
            // restage psL <- pb (part c-major, bf16)
            for (int i = tid; i < 1024; i += 256) {
                int c = i >> 4, s4 = i & 15;
                *(uint2*)&psL[c * SDT_ + s4 * 4] = *(const uint2*)&pb[(size_t)c * 576 + kt * 64 + s4 * 4];
            }
            __syncthreads();
            // phase B: acc2[side] += P[c][sd] * wt[hw][sd]^T
            {
                short8 pA0 = *(const short8*)&psL[(m0 + l15) * SDT_ + quad * 8];
                short8 pA1 = *(const short8*)&psL[(m0 + l15) * SDT_ + 32 + quad * 8];
                #pragma unroll
                for (int tile = 0; tile < 4; ++tile) {
                    short8 wb0 = *(const short8*)&wt[(tile * 16 + l15) * SDT_ + quad * 8];
                    short8 wb1 = *(const short8*)&wt[(tile * 16 + l15) * SDT_ + 32 + quad * 8];
                    acc2[side][tile] = __builtin_amdgcn_mfma_f32_16x16x32_bf16(pA0, wb0, acc2[side][tile], 0, 0, 0);
                    acc2[side][tile] = __builtin_amdgcn_mfma_f32_16x16x32_bf16(pA1, wb1, acc2[side][tile], 0, 0, 0);
                }
            }
        }
    }
    float w20 = weights2[0], w21 = weights2[1];
    #pragma unroll
    for (int tile = 0; tile < 4; ++tile) {
        int thw = base + tile * 16 + l15;
        #pragma unroll
        for (int r = 0; r < 4; ++r) {
            int c = m0 + quad * 4 + r;
            float a = 0.f;
            #pragma unroll
            for (int rr = 0; rr < RC_; ++rr) a += w_back[c * RC_ + rr] * agg0[rr * THW_ + thw];
            out[(size_t)c * THW_ + thw] =
                (acc2[0][tile][r] * w20 + acc2[1][tile][r] * w21) * (sigm(a) - 0.5f);
        }
    }
}

extern "C" void kernel_launch(void* const* d_in, const int* in_sizes, int n_in,
                              void* d_out, int out_size, void* d_ws, size_t ws_size,
                              hipStream_t stream) {
    const float* x       = (const float*)d_in[0];
    const float* w_dc2   = (const float*)d_in[1];
    const float* w_ofs_l = (const float*)d_in[2];
    const float* b_ofs_l = (const float*)d_in[3];
    const float* w_ofs_r = (const float*)d_in[4];
    const float* b_ofs_r = (const float*)d_in[5];
    const float* ca_w1   = (const float*)d_in[6];
    const float* ca_w2   = (const float*)d_in[7];
    const float* w_down  = (const float*)d_in[8];
    const float* sa1_w   = (const float*)d_in[9];
    const float* sa1_b   = (const float*)d_in[10];
    const float* sa2_w   = (const float*)d_in[11];
    const float* sa2_b   = (const float*)d_in[12];
    const float* sa3_w   = (const float*)d_in[13];
    const float* sa3_b   = (const float*)d_in[14];
    const float* weights = (const float*)d_in[15];
    const float* weights2= (const float*)d_in[16];
    const float* w_back  = (const float*)d_in[17];
    float* out = (float*)d_out;

    // workspace ~24.3 MB. x2T region (dead after k_gs) hosts stats/yb/agg0/partb
    // overlays (all written after k_gs). xd lives OUTSIDE the overlay (written by
    // k_pre while x2T is still live).
    float* ws    = (float*)d_ws;
    float* x2T   = ws;                               // CTHW_ f32
    float* stats = x2T;                              // overlay: 221,184 f32
    float* yb    = stats + 2 * 3 * THW_;             // 73,728
    float* agg0  = yb + 2 * THW_;                    // 147,456
    unsigned short* partb = (unsigned short*)(agg0 + RC_ * THW_);  // 1,179,648 u16
    float* off   = ws + CTHW_;                       // 36,864 f32
    unsigned short* xbh = (unsigned short*)(off + 2 * T_ * 2 * SD_);  // CTHW_ u16
    unsigned short* xbl = xbh + CTHW_;                                // CTHW_ u16
    unsigned short* pch = xbl + CTHW_;               // 1,179,648 u16
    unsigned short* pcl = pch + 2 * 16 * 576 * 64;   // 1,179,648 u16
    float* xd    = (float*)(pcl + 2 * 16 * 576 * 64); // 147,456 f32 (NOT overlaid)

    k_pre<<<THW_ / 64, 256, 0, stream>>>(x, w_dc2, w_down, x2T, xbh, xbl, xd);
    k_off<<<(2 * 16 * 576) / 4, 256, 0, stream>>>(x, x2T, w_ofs_l, b_ofs_l,
                                                  w_ofs_r, b_ofs_r, off);
    k_gs<<<(2 * 16 * 576) / 4, 256, 0, stream>>>(x2T, off, pch, pcl);
    k_tr<<<32 * 9, 256, 0, stream>>>(pch, partb);
    k_stats<<<16 * 36, 256, 0, stream>>>(xbh, xbl, pch, pcl, stats);
    k_attn<<<(2 * THW_) / 256, 256, 0, stream>>>(stats, ca_w1, ca_w2, yb);
    k_agg<<<(RC_ * THW_) / 256, 256, 0, stream>>>(xd, sa1_w, sa1_b, sa2_w, sa2_b,
                                                  sa3_w, sa3_b, weights, agg0);
    k_final<<<16 * 36, 256, 0, stream>>>(xbh, xbl, pch, pcl, partb, yb, weights2,
                                         agg0, w_back, out);
}